// Round 12
// baseline (536.253 us; speedup 1.0000x reference)
//
#include <hip/hip_runtime.h>
#include <hip/hip_bf16.h>

#define B_  4
#define L_  2048      // LO == LQ == 2048
#define H_  128
#define NH_ 2
#define G_  10
#define NIN_ 41

typedef __hip_bfloat16 bf16;
typedef __attribute__((ext_vector_type(8))) short bf16x8s;  // 8 bf16 = 4 VGPRs
typedef __attribute__((ext_vector_type(4))) float f32x4;

__device__ __forceinline__ unsigned short f2bf_bits(float x) {
    __hip_bfloat16 h = __float2bfloat16(x);
    return *reinterpret_cast<unsigned short*>(&h);
}
__device__ __forceinline__ float us2f(unsigned short s) {
    return __uint_as_float(((unsigned int)s) << 16);
}

// ---------------------------------------------------------------------------
// K1+K2 merged: featurize query rows (blk < NROW) and obs rows (blk >= NROW)
// ---------------------------------------------------------------------------
__global__ __launch_bounds__(128)
void featall_kernel(const float* __restrict__ xq, const float* __restrict__ mq,
                    const float* __restrict__ obs, const float* __restrict__ mobs,
                    const float* __restrict__ w_q0, const float* __restrict__ b_q0,
                    const float* __restrict__ w_q1, const float* __restrict__ b_q1,
                    const float* __restrict__ w_cq, const float* __restrict__ b_cq,
                    const float* __restrict__ w_o0, const float* __restrict__ b_o0,
                    const float* __restrict__ w_o1, const float* __restrict__ b_o1,
                    const float* __restrict__ w_cobs, const float* __restrict__ b_cobs,
                    bf16* __restrict__ featq, bf16* __restrict__ feato)
{
    const int blk = blockIdx.x;
    const int j   = threadIdx.x;
    const int NROW = B_ * L_;
    if (blk < NROW) {
        const int row = blk;
        const float t   = xq[row * 2 + 0];
        const float chf = xq[row * 2 + 1];
        int ch = (int)chf; ch = max(0, min(NIN_ - 1, ch));
        const float m   = mq[row];
        float tf;
        if (j == 0) tf = t * w_q0[0] + b_q0[0];
        else        tf = __sinf(t * w_q1[j - 1] + b_q1[j - 1]);
        float cf = fmaxf(w_cq[ch * H_ + j] + b_cq[j], 0.f);
        featq[(size_t)row * 256 + j]       = __float2bfloat16(tf * m);
        featq[(size_t)row * 256 + 128 + j] = __float2bfloat16(cf * m);
    } else {
        const int row = blk - NROW;
        const float t   = obs[row * 3 + 0];
        const float chf = obs[row * 3 + 1];
        const float xv  = obs[row * 3 + 2];
        int ch = (int)chf; ch = max(0, min(NIN_ - 1, ch));
        const float m   = mobs[row];
        float tf;
        if (j == 0) tf = t * w_o0[0] + b_o0[0];
        else        tf = __sinf(t * w_o1[j - 1] + b_o1[j - 1]);
        float cf = fmaxf(w_cobs[ch * H_ + j] + b_cobs[j], 0.f);
        bf16* r = feato + (size_t)row * 288;
        r[j]       = __float2bfloat16(tf * m);
        r[128 + j] = __float2bfloat16(cf * m);
        if (j == 0) r[256] = __float2bfloat16(xv * m);
        if (j < 31) r[257 + j] = __float2bfloat16(0.f);
    }
}

// ---------------------------------------------------------------------------
// All weight transposes (fp32 K x N -> bf16 N x Kp, zero pad k>=K) in 1 launch
// ---------------------------------------------------------------------------
struct WtArgs {
    const float* W[8];
    bf16* T[8];
    int K[8], Kp[8], N[8];
};
__global__ __launch_bounds__(288)
void wtrans_all_kernel(WtArgs a)
{
    const int i = blockIdx.y, n = blockIdx.x, k = threadIdx.x;
    if (n >= a.N[i] || k >= a.Kp[i]) return;
    a.T[i][(size_t)n * a.Kp[i] + k] =
        (k < a.K[i]) ? __float2bfloat16(a.W[i][(size_t)k * a.N[i] + n])
                     : __float2bfloat16(0.f);
}

// ---------------------------------------------------------------------------
// KV transpose v2: in (BH, L, H) -> out (BH, H, L). 32-row tiles,
// grid (L/32, BH) = 512 blocks (was 256) for better tail/occupancy.
// ---------------------------------------------------------------------------
__global__ __launch_bounds__(256)
void kvtrans_kernel(const bf16* __restrict__ in, bf16* __restrict__ out)
{
    __shared__ unsigned short tile[32 * 136];
    const int tid = threadIdx.x;
    const int l0 = blockIdx.x * 32;
    const int bh = blockIdx.y;
    const unsigned short* src = (const unsigned short*)(in + (size_t)bh * L_ * H_);
    unsigned short* dst = (unsigned short*)(out + (size_t)bh * H_ * L_);
    #pragma unroll
    for (int p = 0; p < 2; p++) {
        const int l = p * 16 + (tid >> 4);
        const int d0 = (tid & 15) * 8;
        *(uint4*)&tile[l * 136 + d0] = *(const uint4*)&src[(size_t)(l0 + l) * H_ + d0];
    }
    __syncthreads();
    const int d  = tid >> 1;
    const int lh = (tid & 1) * 16;
    unsigned short buf[16];
    #pragma unroll
    for (int j = 0; j < 16; j++) buf[j] = tile[(lh + j) * 136 + d];
    #pragma unroll
    for (int j = 0; j < 2; j++)
        *(uint4*)&dst[(size_t)d * L_ + l0 + lh + j * 8] = *(uint4*)&buf[j * 8];
}

// ---------------------------------------------------------------------------
// GEMM v3 (LDS stage-once, half-height tiles for occupancy):
// C = A(bf16 M x K) @ WT(bf16 N x K) + bias(fp32), optional bf16 residual R.
// Block = 128 thr = 2 waves, tile 32x64. ONE barrier, barrier-free MFMA loop.
// Grid (M/32, N/64). K multiple of 32, K <= 288.
// out modes: 0 fp32 row-major, 1 bf16 row-major, 2 bf16 per-head (B,NH,L,H),
//            3 fp32 split-transposed (B,G,L,H).
// ---------------------------------------------------------------------------
__global__ __launch_bounds__(128)
void gemm_kernel(const bf16* __restrict__ A, const bf16* __restrict__ WT,
                 const float* __restrict__ bias, const bf16* __restrict__ R,
                 void* __restrict__ out, int K, int N, int mode, int do_relu)
{
    __shared__ __align__(16) unsigned short As[32 * 296];   // 18944 B max
    __shared__ __align__(16) unsigned short Ws[64 * 296];   // 37888 B max

    const int tid  = threadIdx.x;
    const int wave = tid >> 6, lane = tid & 63;
    const int quad = lane >> 4, l15 = lane & 15;
    const int m0 = blockIdx.x * 32;
    const int n0 = blockIdx.y * 64;
    const int Kp = K + 8;

    // ---- stage tiles: 4 thr/row, 64B-coalesced groups ----
    const int srow = tid >> 2;           // 0..31
    const int sc0  = (tid & 3) * 8;
    {
        const bf16* arow = A  + (size_t)(m0 + srow) * K;
        const bf16* w0   = WT + (size_t)(n0 + srow) * K;
        const bf16* w1   = WT + (size_t)(n0 + 32 + srow) * K;
        for (int col = sc0; col < K; col += 32) {
            *(uint4*)&As[srow * Kp + col]        = *(const uint4*)(arow + col);
            *(uint4*)&Ws[srow * Kp + col]        = *(const uint4*)(w0 + col);
            *(uint4*)&Ws[(32 + srow) * Kp + col] = *(const uint4*)(w1 + col);
        }
    }
    __syncthreads();

    f32x4 acc[4];
    #pragma unroll
    for (int c = 0; c < 4; c++) acc[c] = (f32x4){0.f, 0.f, 0.f, 0.f};

    const unsigned short* am = &As[(wave * 16 + l15) * Kp + quad * 8];
    #pragma unroll 4
    for (int kc = 0; kc < K; kc += 32) {
        bf16x8s af = *(const bf16x8s*)(am + kc);
        #pragma unroll
        for (int c = 0; c < 4; c++) {
            bf16x8s wf = *(const bf16x8s*)&Ws[(c * 16 + l15) * Kp + kc + quad * 8];
            acc[c] = __builtin_amdgcn_mfma_f32_16x16x32_bf16(af, wf, acc[c], 0, 0, 0);
        }
    }

    const int mw0 = m0 + wave * 16;
    #pragma unroll
    for (int c = 0; c < 4; c++) {
        const int n = n0 + c * 16 + l15;
        const float bv = bias[n];
        #pragma unroll
        for (int r = 0; r < 4; r++) {
            const int m = mw0 + quad * 4 + r;
            float v = acc[c][r] + bv;
            if (R != nullptr) v += __bfloat162float(R[(size_t)m * N + n]);
            if (do_relu) v = fmaxf(v, 0.f);
            if (mode == 0) {
                ((float*)out)[(size_t)m * N + n] = v;
            } else if (mode == 1) {
                ((bf16*)out)[(size_t)m * N + n] = __float2bfloat16(v);
            } else if (mode == 2) {
                const int b = m >> 11, l = m & 2047, hh = n >> 7, d = n & 127;
                ((bf16*)out)[(((size_t)(b * NH_ + hh)) * L_ + l) * H_ + d] = __float2bfloat16(v);
            } else {
                const int b = m >> 11, q = m & 2047, g = n >> 7, hh = n & 127;
                ((float*)out)[(((size_t)(b * G_ + g)) * L_ + q) * H_ + hh] = v;
            }
        }
    }
}

// ---------------------------------------------------------------------------
// Flash attention v7 (PROVEN, Round-7/9/10/11 bytes): LDS-cooperative
// restaging. FROZEN: every variant (wider q-rows r3, ones-MFMA r4, XOR
// swizzle r5/r6, 256-thr r8) pushed peak live-VGPR past the allocator's
// threshold -> scratch pathology (>100 MB scratch writes).
// Canary: WRITE_SIZE >> 4 MB.
// ---------------------------------------------------------------------------
#define KT_S 136    // K tile row stride (shorts): 272 B, 16B-aligned
#define VT_S 72     // V^T tile row stride (shorts): 144 B, 16B-aligned
#define PS_S 72     // P row stride (shorts)

__global__ __launch_bounds__(512, 2)
void flash_attn_kernel(const bf16* __restrict__ Qb, const bf16* __restrict__ KVb,
                       const bf16* __restrict__ KVTb,
                       const float* __restrict__ mQ, const float* __restrict__ mK,
                       bf16* __restrict__ O)
{
    __shared__ __align__(16) char smem[90112];
    unsigned short* Ks = (unsigned short*)smem;
    unsigned short* Vs = (unsigned short*)(smem + 34816);
    unsigned short* Ps = (unsigned short*)(smem + 71680);
    float* Ocomb = (float*)smem;
    float* mcomb = (float*)(smem + 33792);
    float* lcomb = (float*)(smem + 34048);

    const int tid  = threadIdx.x;
    const int lane = tid & 63;
    const int wave = tid >> 6;         // 0..7
    const int half = wave >> 2;        // K-split half
    const int wq   = wave & 3;         // q sub-tile within block
    const int quad = lane >> 4;
    const int l15  = lane & 15;
    const int t256 = tid & 255;        // staging id within half
    const int bh = blockIdx.x, b = bh >> 1, h = bh & 1;
    const int q0 = blockIdx.y * 64;

    const bf16* kvb = KVb  + (size_t)bh * L_ * H_;
    const bf16* kvt = KVTb + (size_t)bh * H_ * L_;
    const float* mkb = mK + b * L_;

    const bf16* qrow = Qb + ((size_t)bh * L_ + q0 + wq * 16 + l15) * H_;
    bf16x8s qf[4];
    #pragma unroll
    for (int kc = 0; kc < 4; kc++)
        qf[kc] = *(const bf16x8s*)(qrow + kc * 32 + quad * 8);

    bool qz[4];
    #pragma unroll
    for (int r = 0; r < 4; r++)
        qz[r] = (mQ != nullptr) && (mQ[b * L_ + q0 + wq * 16 + quad * 4 + r] == 0.f);

    float mo[4], li[4];
    f32x4 Oacc[8];
    #pragma unroll
    for (int r = 0; r < 4; r++) { mo[r] = -1e30f; li[r] = 0.f; }
    #pragma unroll
    for (int c = 0; c < 8; c++) Oacc[c] = (f32x4){0.f, 0.f, 0.f, 0.f};

    const float SCALE = 0.08838834764831845f;    // 1/sqrt(128)
    unsigned short* KsH = Ks + half * 64 * KT_S;
    unsigned short* VsH = Vs + half * 128 * VT_S;
    unsigned short* pw  = Ps + wave * 16 * PS_S;

    const int krow_b = t256 >> 4, kcol = (t256 & 15) * 8;   // K: 16 thr/row
    const int vrow_b = t256 >> 3, vcol = (t256 & 7) * 8;    // V: 8 thr/row

    uint4 rk[4], rv[4];
    const int ks0 = half * 1024;

    {
        const int kb = ks0;
        #pragma unroll
        for (int p = 0; p < 4; p++)
            rk[p] = *(const uint4*)(kvb + (size_t)(kb + p * 16 + krow_b) * H_ + kcol);
        #pragma unroll
        for (int p = 0; p < 4; p++)
            rv[p] = *(const uint4*)(kvt + (size_t)(p * 32 + vrow_b) * L_ + kb + vcol);
        #pragma unroll
        for (int p = 0; p < 4; p++)
            *(uint4*)&KsH[(p * 16 + krow_b) * KT_S + kcol] = rk[p];
        #pragma unroll
        for (int p = 0; p < 4; p++)
            *(uint4*)&VsH[(p * 32 + vrow_b) * VT_S + vcol] = rv[p];
    }
    __syncthreads();

    for (int it = 0; it < 16; it++) {
        const int kb = ks0 + it * 64;

        if (it + 1 < 16) {
            const int kn = kb + 64;
            #pragma unroll
            for (int p = 0; p < 4; p++)
                rk[p] = *(const uint4*)(kvb + (size_t)(kn + p * 16 + krow_b) * H_ + kcol);
            #pragma unroll
            for (int p = 0; p < 4; p++)
                rv[p] = *(const uint4*)(kvt + (size_t)(p * 32 + vrow_b) * L_ + kn + vcol);
        }

        float koff[4];
        #pragma unroll
        for (int t = 0; t < 4; t++)
            koff[t] = (mkb[kb + t * 16 + l15] != 0.f) ? 0.f : -1000000.f;

        f32x4 sa[4];
        #pragma unroll
        for (int t = 0; t < 4; t++) sa[t] = (f32x4){0.f, 0.f, 0.f, 0.f};
        #pragma unroll
        for (int t = 0; t < 4; t++)
            #pragma unroll
            for (int kc = 0; kc < 4; kc++) {
                bf16x8s kf = *(const bf16x8s*)&KsH[(t * 16 + l15) * KT_S + kc * 32 + quad * 8];
                sa[t] = __builtin_amdgcn_mfma_f32_16x16x32_bf16(qf[kc], kf, sa[t], 0, 0, 0);
            }

        float s[4][4], mx[4];
        #pragma unroll
        for (int r = 0; r < 4; r++) {
            #pragma unroll
            for (int t = 0; t < 4; t++) {
                const float v = sa[t][r] * SCALE + koff[t];
                s[t][r] = qz[r] ? -1000000.f : v;   // exact -1e6 for masked queries
            }
            mx[r] = fmaxf(fmaxf(s[0][r], s[1][r]), fmaxf(s[2][r], s[3][r]));
        }
        #pragma unroll
        for (int off = 1; off < 16; off <<= 1)
            #pragma unroll
            for (int r = 0; r < 4; r++) mx[r] = fmaxf(mx[r], __shfl_xor(mx[r], off));

        float al[4], rs[4];
        #pragma unroll
        for (int r = 0; r < 4; r++) {
            const float mn = fmaxf(mo[r], mx[r]);
            al[r] = __expf(mo[r] - mn);
            mo[r] = mn;
            rs[r] = 0.f;
        }
        #pragma unroll
        for (int t = 0; t < 4; t++)
            #pragma unroll
            for (int r = 0; r < 4; r++) {
                const float p = __expf(s[t][r] - mo[r]);
                rs[r] += p;
                pw[(quad * 4 + r) * PS_S + t * 16 + l15] = f2bf_bits(p);
            }
        #pragma unroll
        for (int off = 1; off < 16; off <<= 1)
            #pragma unroll
            for (int r = 0; r < 4; r++) rs[r] += __shfl_xor(rs[r], off);
        #pragma unroll
        for (int r = 0; r < 4; r++) li[r] = li[r] * al[r] + rs[r];
        #pragma unroll
        for (int c = 0; c < 8; c++)
            #pragma unroll
            for (int r = 0; r < 4; r++) Oacc[c][r] *= al[r];

        bf16x8s pf0 = *(bf16x8s*)&pw[l15 * PS_S + quad * 8];
        bf16x8s pf1 = *(bf16x8s*)&pw[l15 * PS_S + 32 + quad * 8];

        #pragma unroll
        for (int c = 0; c < 8; c++) {
            bf16x8s v0 = *(const bf16x8s*)&VsH[(c * 16 + l15) * VT_S + quad * 8];
            bf16x8s v1 = *(const bf16x8s*)&VsH[(c * 16 + l15) * VT_S + 32 + quad * 8];
            Oacc[c] = __builtin_amdgcn_mfma_f32_16x16x32_bf16(pf0, v0, Oacc[c], 0, 0, 0);
            Oacc[c] = __builtin_amdgcn_mfma_f32_16x16x32_bf16(pf1, v1, Oacc[c], 0, 0, 0);
        }

        __syncthreads();                       // all waves done reading tiles
        if (it + 1 < 16) {
            #pragma unroll
            for (int p = 0; p < 4; p++)
                *(uint4*)&KsH[(p * 16 + krow_b) * KT_S + kcol] = rk[p];
            #pragma unroll
            for (int p = 0; p < 4; p++)
                *(uint4*)&VsH[(p * 32 + vrow_b) * VT_S + vcol] = rv[p];
            __syncthreads();
        }
    }

    if (half == 1) {
        #pragma unroll
        for (int c = 0; c < 8; c++)
            #pragma unroll
            for (int r = 0; r < 4; r++)
                Ocomb[(size_t)(wq * 16 + quad * 4 + r) * 132 + c * 16 + l15] = Oacc[c][r];
        if (l15 == 0) {
            #pragma unroll
            for (int r = 0; r < 4; r++) {
                mcomb[wq * 16 + quad * 4 + r] = mo[r];
                lcomb[wq * 16 + quad * 4 + r] = li[r];
            }
        }
    }
    __syncthreads();
    if (half == 0) {
        bf16* orow = O + ((size_t)b * L_ + q0 + wq * 16) * (NH_ * H_) + h * H_;
        #pragma unroll
        for (int r = 0; r < 4; r++) {
            const int row = quad * 4 + r;
            const float m1 = mcomb[wq * 16 + row];
            const float l1 = lcomb[wq * 16 + row];
            const float M  = fmaxf(mo[r], m1);
            const float a0 = __expf(mo[r] - M);
            const float a1 = __expf(m1 - M);
            const float inv = 1.f / (a0 * li[r] + a1 * l1);
            #pragma unroll
            for (int c = 0; c < 8; c++)
                orow[(size_t)row * (NH_ * H_) + c * 16 + l15] =
                    __float2bfloat16((a0 * Oacc[c][r] +
                                      a1 * Ocomb[(size_t)(wq * 16 + row) * 132 + c * 16 + l15]) * inv);
        }
    }
}

// ---------------------------------------------------------------------------
// qmw builder: mix_wt(10x128) @ ww_q(128x256) + b -> bf16 per-head (2,16,128)
// ---------------------------------------------------------------------------
__global__ __launch_bounds__(256)
void qmwb_kernel(const float* __restrict__ mixwt, const float* __restrict__ W,
                 const float* __restrict__ bias, bf16* __restrict__ qmwb)
{
    const int g = blockIdx.x;          // 0..15
    const int c = threadIdx.x;         // 0..255
    const int h = c >> 7, d = c & 127;
    if (g >= G_) { qmwb[((size_t)h * 16 + g) * 128 + d] = __float2bfloat16(0.f); return; }
    __shared__ float xr[128];
    if (c < 128) xr[c] = mixwt[g * 128 + c];
    __syncthreads();
    float acc = bias[c];
    #pragma unroll 8
    for (int i = 0; i < 128; i++)
        acc += xr[i] * W[i * 256 + c];
    qmwb[((size_t)h * 16 + g) * 128 + d] = __float2bfloat16(acc);
}

// ---------------------------------------------------------------------------
// mw partial attention v2: 32-way K-split (64-key tiles).
// grid (32, NH, B) = 256 blocks (was 128 -> half the GPU idle), 256 threads.
// ---------------------------------------------------------------------------
__global__ __launch_bounds__(256)
void mwpartial_kernel(const bf16* __restrict__ qmwb, const bf16* __restrict__ kvmw,
                      const float* __restrict__ mK,
                      float* __restrict__ mwO, float* __restrict__ mwM,
                      float* __restrict__ mwL)
{
    __shared__ __align__(16) unsigned short Ks[64 * 136];
    __shared__ float Qs[10 * 128];
    __shared__ float sc[10 * 64];
    __shared__ float mst[10], lst[10];

    const int tid = threadIdx.x;
    const int split = blockIdx.x, h = blockIdx.y, b = blockIdx.z;
    const int kbase = split * 64;
    const float SCALE = 0.08838834764831845f;

    for (int idx = tid; idx < 1280; idx += 256)
        Qs[idx] = __bfloat162float(qmwb[((size_t)h * 16 + (idx >> 7)) * 128 + (idx & 127)]);
    {
        const int rr = tid >> 2, qt = tid & 3;   // 64 rows, 4 thr/row
        const bf16* src = kvmw + (((size_t)(b * NH_ + h)) * L_ + kbase + rr) * H_ + qt * 32;
        #pragma unroll
        for (int i = 0; i < 4; i++)
            *(uint4*)(&Ks[rr * 136 + qt * 32 + i * 8]) = *(const uint4*)(src + i * 8);
    }
    __syncthreads();

    {
        const int j = tid & 63, qg = tid >> 6;   // key j, query-group qg 0..3
        float acc[3] = {0.f, 0.f, 0.f};
        for (int dc = 0; dc < 128; dc += 8) {
            bf16x8s kv = *(bf16x8s*)(&Ks[j * 136 + dc]);
            float kf[8];
            #pragma unroll
            for (int e = 0; e < 8; e++) kf[e] = us2f(((unsigned short*)&kv)[e]);
            #pragma unroll
            for (int qq = 0; qq < 3; qq++) {
                const int q = qg + 4 * qq;       // {qg, qg+4, qg+8}
                if (q < G_) {
                    const float* Qrow = &Qs[q * 128 + dc];
                    #pragma unroll
                    for (int e = 0; e < 8; e++) acc[qq] += Qrow[e] * kf[e];
                }
            }
        }
        const bool kz = (mK[b * L_ + kbase + j] == 0.f);
        #pragma unroll
        for (int qq = 0; qq < 3; qq++) {
            const int q = qg + 4 * qq;
            if (q < G_) sc[q * 64 + j] = kz ? -1000000.f : acc[qq] * SCALE;
        }
    }
    __syncthreads();
    if (tid < 160) {
        const int q = tid >> 4, t16 = tid & 15;
        float m = -3.4e38f;
        for (int jj = t16; jj < 64; jj += 16) m = fmaxf(m, sc[q * 64 + jj]);
        #pragma unroll
        for (int off = 1; off < 16; off <<= 1) m = fmaxf(m, __shfl_xor(m, off));
        if (t16 == 0) mst[q] = m;
    }
    __syncthreads();
    for (int idx = tid; idx < 640; idx += 256)
        sc[idx] = __expf(sc[idx] - mst[idx >> 6]);
    __syncthreads();
    if (tid < 160) {
        const int q = tid >> 4, t16 = tid & 15;
        float s = 0.f;
        for (int jj = t16; jj < 64; jj += 16) s += sc[q * 64 + jj];
        #pragma unroll
        for (int off = 1; off < 16; off <<= 1) s += __shfl_xor(s, off);
        if (t16 == 0) lst[q] = s;
    }
    __syncthreads();
    {
        const int d = tid & 127, qh = tid >> 7;  // 0..1, 5 queries each
        float acc[5] = {0.f, 0.f, 0.f, 0.f, 0.f};
        for (int jj = 0; jj < 64; jj++) {
            const float v = us2f(Ks[jj * 136 + d]);
            #pragma unroll
            for (int qq = 0; qq < 5; qq++)
                acc[qq] += sc[(qh * 5 + qq) * 64 + jj] * v;
        }
        const size_t base = ((size_t)(b * NH_ + h) * 32 + split) * 10;
        #pragma unroll
        for (int qq = 0; qq < 5; qq++)
            mwO[(base + qh * 5 + qq) * 128 + d] = acc[qq];
    }
    if (tid < 10) {
        const size_t base = ((size_t)(b * NH_ + h) * 32 + split) * 10;
        mwM[base + tid] = mst[tid];
        mwL[base + tid] = lst[tid];
    }
}

// ---------------------------------------------------------------------------
// mw tail (FUSED mwcombine+mwproj+mwfinal): grid B_, 256 threads.
// Combines 32 K-splits (was 16).
// ---------------------------------------------------------------------------
__global__ __launch_bounds__(256)
void mwtail_kernel(const float* __restrict__ mwO, const float* __restrict__ mwM,
                   const float* __restrict__ mwL, const float* __restrict__ mixwt,
                   const float* __restrict__ W, const float* __restrict__ bias,
                   const float* __restrict__ wmix, const float* __restrict__ bmix,
                   float* __restrict__ out)
{
    __shared__ float mwat[10][256];
    __shared__ float mwq[10][128];
    __shared__ float zz[10];

    const int b = blockIdx.x, tid = threadIdx.x;
    const int h = tid >> 7, d = tid & 127;

    // combine: thread (h,d) handles column h*128+d of all 10 queries
    const size_t hb = (size_t)(b * NH_ + h) * 32;
    for (int q = 0; q < G_; q++) {
        float M = -3.4e38f;
        for (int s = 0; s < 32; s++) M = fmaxf(M, mwM[(hb + s) * 10 + q]);
        float l = 0.f, o = 0.f;
        for (int s = 0; s < 32; s++) {
            const float a = __expf(mwM[(hb + s) * 10 + q] - M);
            l += a * mwL[(hb + s) * 10 + q];
            o += a * mwO[((hb + s) * 10 + q) * 128 + d];
        }
        mwat[q][h * 128 + d] = o / l;
    }
    __syncthreads();

    // proj: thread handles q in {h, h+2, ..., h+8}, output dim d
    #pragma unroll
    for (int j = 0; j < 5; j++) {
        const int q = h + 2 * j;
        float acc = mixwt[q * 128 + d] + bias[d];
        #pragma unroll 8
        for (int i = 0; i < 256; i++)
            acc += mwat[q][i] * W[i * 128 + d];
        mwq[q][d] = acc;
    }
    __syncthreads();

    // final: z[q] = dot(mwq[q], wmix) + b ; softmax over q
    if (tid < G_) {
        float acc = bmix[0];
        for (int i = 0; i < 128; i++)
            acc += mwq[tid][i] * wmix[i];
        zz[tid] = acc;
    }
    __syncthreads();
    if (tid == 0) {
        float mx = -3.4e38f;
        for (int i = 0; i < G_; i++) mx = fmaxf(mx, zz[i]);
        float e[G_]; float s = 0.f;
        for (int i = 0; i < G_; i++) { e[i] = __expf(zz[i] - mx); s += e[i]; }
        for (int i = 0; i < G_; i++) out[b * G_ + i] = e[i] / s;
    }
}

// ---------------------------------------------------------------------------
extern "C" void kernel_launch(void* const* d_in, const int* in_sizes, int n_in,
                              void* d_out, int out_size, void* d_ws, size_t ws_size,
                              hipStream_t stream)
{
    const float* obs    = (const float*)d_in[0];
    const float* mobs   = (const float*)d_in[1];
    const float* xq     = (const float*)d_in[2];
    const float* mq     = (const float*)d_in[3];
    const float* w_q0   = (const float*)d_in[4];
    const float* b_q0   = (const float*)d_in[5];
    const float* w_q1   = (const float*)d_in[6];
    const float* b_q1   = (const float*)d_in[7];
    const float* w_o0   = (const float*)d_in[8];
    const float* b_o0   = (const float*)d_in[9];
    const float* w_o1   = (const float*)d_in[10];
    const float* b_o1   = (const float*)d_in[11];
    const float* w_cobs = (const float*)d_in[12];
    const float* b_cobs = (const float*)d_in[13];
    const float* w_cq   = (const float*)d_in[14];
    const float* b_cq   = (const float*)d_in[15];
    const float* w_qp   = (const float*)d_in[16];
    const float* b_qp   = (const float*)d_in[17];
    const float* w_kp   = (const float*)d_in[18];
    const float* b_kp   = (const float*)d_in[19];
    const float* ws_q   = (const float*)d_in[20];
    const float* ws_qb  = (const float*)d_in[21];
    const float* ws_o   = (const float*)d_in[22];
    const float* ws_ob  = (const float*)d_in[23];
    const float* ww_q   = (const float*)d_in[24];
    const float* ww_qb  = (const float*)d_in[25];
    const float* ww_o   = (const float*)d_in[26];
    const float* ww_ob  = (const float*)d_in[27];
    const float* wc_q   = (const float*)d_in[28];
    const float* wc_qb  = (const float*)d_in[29];
    const float* wc_o   = (const float*)d_in[30];
    const float* wc_ob  = (const float*)d_in[31];
    const float* w_split= (const float*)d_in[32];
    const float* b_split= (const float*)d_in[33];
    const float* mix_wt = (const float*)d_in[34];
    const float* w_mix  = (const float*)d_in[35];
    const float* b_mix  = (const float*)d_in[36];

    float* out = (float*)d_out;
    char* ws  = (char*)d_ws;

    const size_t MB = (size_t)1 << 20;
    const size_t KB = (size_t)1 << 10;
    if (ws_size < 31 * MB) return;

    const int NROW = B_ * L_;          // 8192
    // layout (<=31 MB). qcb+kvcb and qe_bf+x_bf pairs MUST be contiguous.
    bf16* featq = (bf16*)(ws + 0);                 // 4 MB  -> kvbs, later qcb
    bf16* feato = (bf16*)(ws + 4 * MB);            // 4.5 MB -> later kvcb (at +4MB!)
    bf16* qe_bf = (bf16*)(ws + 8 * MB + 512 * KB); // 2 MB  \ contiguous pair
    bf16* x_bf  = (bf16*)(ws + 10 * MB + 512 * KB);// 2 MB  / for merged gemm
    bf16* oe_bf = (bf16*)(ws + 12 * MB + 512 * KB);// 2 MB
    bf16* abuf  = (bf16*)(ws + 14 * MB + 512 * KB);// 4 MB -> abuf2
    bf16* x2_bf = (bf16*)(ws + 18 * MB + 512 * KB);// 2 MB
    bf16* kvmw  = (bf16*)(ws + 20 * MB + 512 * KB);// 4 MB
    bf16* kvT   = (bf16*)(ws + 24 * MB + 512 * KB);// 4 MB (BH,H,L), self then cross
    char* wbase = ws + 28 * MB + 512 * KB;         // ~2.5 MB of weights/smalls
    bf16* wqpT  = (bf16*)(wbase + 0);              // 64 KB (128 x 256)
    bf16* wkpT  = (bf16*)(wbase + 64 * KB);        // 72 KB (128 x 288)
    bf16* wsqT  = (bf16*)(wbase + 136 * KB);       // 64 KB (256 x 128)
    bf16* wsoT  = (bf16*)(wbase + 200 * KB);       // 64 KB (128 x 256)
    bf16* wwqT  = (bf16*)(wbase + 264 * KB);       // 64 KB
    bf16* wcqT  = (bf16*)(wbase + 328 * KB);       // 64 KB
    bf16* wcoT  = (bf16*)(wbase + 392 * KB);       // 64 KB
    bf16* wsplT = (bf16*)(wbase + 456 * KB);       // 320 KB (1280 x 128)
    bf16* qmwb  = (bf16*)(wbase + 776 * KB);       // 8 KB (2,16,128)
    float* mwO  = (float*)(wbase + 784 * KB);      // 1280 KB (B,NH,32,10,128) fp32
    float* mwM  = (float*)(wbase + 2064 * KB);     // 10 KB
    float* mwL  = (float*)(wbase + 2080 * KB);     // 10 KB
    bf16* kvbs  = featq;                           // self QKV (B,NH,L,H)
    bf16* qcb   = featq;                           // cross Q  (B,NH,L,H)
    bf16* kvcb  = (bf16*)(ws + 4 * MB);            // cross KV = qcb + 4MB
    bf16* abuf2 = abuf;

    // 0: all weight transposes in one launch
    WtArgs wa;
    wa.W[0]=w_qp;   wa.T[0]=wqpT;  wa.K[0]=256; wa.Kp[0]=256; wa.N[0]=128;
    wa.W[1]=w_kp;   wa.T[1]=wkpT;  wa.K[1]=257; wa.Kp[1]=288; wa.N[1]=128;
    wa.W[2]=ws_q;   wa.T[2]=wsqT;  wa.K[2]=128; wa.Kp[2]=128; wa.N[2]=256;
    wa.W[3]=ws_o;   wa.T[3]=wsoT;  wa.K[3]=256; wa.Kp[3]=256; wa.N[3]=128;
    wa.W[4]=ww_q;   wa.T[4]=wwqT;  wa.K[4]=128; wa.Kp[4]=128; wa.N[4]=256;
    wa.W[5]=wc_q;   wa.T[5]=wcqT;  wa.K[5]=128; wa.Kp[5]=128; wa.N[5]=256;
    wa.W[6]=wc_o;   wa.T[6]=wcoT;  wa.K[6]=256; wa.Kp[6]=256; wa.N[6]=128;
    wa.W[7]=w_split;wa.T[7]=wsplT; wa.K[7]=128; wa.Kp[7]=128; wa.N[7]=1280;
    wtrans_all_kernel<<<dim3(1280, 8), 288, 0, stream>>>(wa);

    // qmw query builder (depends only on inputs; fills pipeline gap early)
    qmwb_kernel<<<16, 256, 0, stream>>>(mix_wt, ww_q, ww_qb, qmwb);

    // 1-2: featurize (merged)
    featall_kernel<<<2 * NROW, 128, 0, stream>>>(xq, mq, obs, mobs,
                                                 w_q0, b_q0, w_q1, b_q1, w_cq, b_cq,
                                                 w_o0, b_o0, w_o1, b_o1, w_cobs, b_cobs,
                                                 featq, feato);
    // 3-4: embed projections (MFMA, 32x64-tile LDS gemm)
    gemm_kernel<<<dim3(NROW/32, 2), 128, 0, stream>>>(featq, wqpT, b_qp, nullptr,
                                                      qe_bf, 256, 128, 1, 0);
    gemm_kernel<<<dim3(NROW/32, 2), 128, 0, stream>>>(feato, wkpT, b_kp, nullptr,
                                                      oe_bf, 288, 128, 1, 0);
    // 5: self-attn shared q=k=v projection (per-head bf16) + transpose
    gemm_kernel<<<dim3(NROW/32, 4), 128, 0, stream>>>(oe_bf, wsqT, ws_qb, nullptr,
                                                      kvbs, 128, 256, 2, 0);
    kvtrans_kernel<<<dim3(L_/32, B_*NH_), 256, 0, stream>>>(kvbs, kvT);
    // 6: self attention (flash v7)
    flash_attn_kernel<<<dim3(B_*NH_, L_/64), 512, 0, stream>>>(kvbs, kvbs, kvT,
                                                               nullptr, mobs, abuf);
    // 7: x = relu(oe + attn @ ws_o + ws_ob)
    gemm_kernel<<<dim3(NROW/32, 2), 128, 0, stream>>>(abuf, wsoT, ws_ob, oe_bf,
                                                      x_bf, 256, 128, 1, 1);
    // 8-13: mixing-weights path
    gemm_kernel<<<dim3(NROW/32, 4), 128, 0, stream>>>(x_bf, wwqT, ww_qb, nullptr,
                                                      kvmw, 128, 256, 2, 0);
    mwpartial_kernel<<<dim3(32, NH_, B_), 256, 0, stream>>>(qmwb, kvmw, mobs,
                                                            mwO, mwM, mwL);
    mwtail_kernel<<<B_, 256, 0, stream>>>(mwO, mwM, mwL, mix_wt, ww_o, ww_ob,
                                          w_mix, b_mix,
                                          out + (size_t)B_ * G_ * L_ * H_);
    // 14: merged cross projections: [qe_bf; x_bf](16384x128) @ wc_q -> [qcb; kvcb]
    gemm_kernel<<<dim3(2*NROW/32, 4), 128, 0, stream>>>(qe_bf, wcqT, wc_qb, nullptr,
                                                        qcb, 128, 256, 2, 0);
    kvtrans_kernel<<<dim3(L_/32, B_*NH_), 256, 0, stream>>>(kvcb, kvT);
    // 16: cross attention
    flash_attn_kernel<<<dim3(B_*NH_, L_/64), 512, 0, stream>>>(qcb, kvcb, kvT,
                                                               mq, mobs, abuf2);
    // 17: x2 = relu(qe + attn2 @ wc_o + wc_ob)
    gemm_kernel<<<dim3(NROW/32, 2), 128, 0, stream>>>(abuf2, wcoT, wc_ob, qe_bf,
                                                      x2_bf, 256, 128, 1, 1);
    // 18: split + transpose store (MFMA)
    gemm_kernel<<<dim3(NROW/32, 20), 128, 0, stream>>>(x2_bf, wsplT, b_split, nullptr,
                                                       out, 128, 1280, 3, 0);

    (void)in_sizes; (void)n_in; (void)out_size;
}

// Round 13
// 491.250 us; speedup vs baseline: 1.0916x; 1.0916x over previous
//
#include <hip/hip_runtime.h>
#include <hip/hip_bf16.h>

#define B_  4
#define L_  2048      // LO == LQ == 2048
#define H_  128
#define NH_ 2
#define G_  10
#define NIN_ 41

typedef __hip_bfloat16 bf16;
typedef __attribute__((ext_vector_type(8))) short bf16x8s;  // 8 bf16 = 4 VGPRs
typedef __attribute__((ext_vector_type(4))) float f32x4;

__device__ __forceinline__ unsigned short f2bf_bits(float x) {
    __hip_bfloat16 h = __float2bfloat16(x);
    return *reinterpret_cast<unsigned short*>(&h);
}
__device__ __forceinline__ float us2f(unsigned short s) {
    return __uint_as_float(((unsigned int)s) << 16);
}

// ---------------------------------------------------------------------------
// K1+K2 merged: featurize query rows (blk < NROW) and obs rows (blk >= NROW)
// ---------------------------------------------------------------------------
__global__ __launch_bounds__(128)
void featall_kernel(const float* __restrict__ xq, const float* __restrict__ mq,
                    const float* __restrict__ obs, const float* __restrict__ mobs,
                    const float* __restrict__ w_q0, const float* __restrict__ b_q0,
                    const float* __restrict__ w_q1, const float* __restrict__ b_q1,
                    const float* __restrict__ w_cq, const float* __restrict__ b_cq,
                    const float* __restrict__ w_o0, const float* __restrict__ b_o0,
                    const float* __restrict__ w_o1, const float* __restrict__ b_o1,
                    const float* __restrict__ w_cobs, const float* __restrict__ b_cobs,
                    bf16* __restrict__ featq, bf16* __restrict__ feato)
{
    const int blk = blockIdx.x;
    const int j   = threadIdx.x;
    const int NROW = B_ * L_;
    if (blk < NROW) {
        const int row = blk;
        const float t   = xq[row * 2 + 0];
        const float chf = xq[row * 2 + 1];
        int ch = (int)chf; ch = max(0, min(NIN_ - 1, ch));
        const float m   = mq[row];
        float tf;
        if (j == 0) tf = t * w_q0[0] + b_q0[0];
        else        tf = __sinf(t * w_q1[j - 1] + b_q1[j - 1]);
        float cf = fmaxf(w_cq[ch * H_ + j] + b_cq[j], 0.f);
        featq[(size_t)row * 256 + j]       = __float2bfloat16(tf * m);
        featq[(size_t)row * 256 + 128 + j] = __float2bfloat16(cf * m);
    } else {
        const int row = blk - NROW;
        const float t   = obs[row * 3 + 0];
        const float chf = obs[row * 3 + 1];
        const float xv  = obs[row * 3 + 2];
        int ch = (int)chf; ch = max(0, min(NIN_ - 1, ch));
        const float m   = mobs[row];
        float tf;
        if (j == 0) tf = t * w_o0[0] + b_o0[0];
        else        tf = __sinf(t * w_o1[j - 1] + b_o1[j - 1]);
        float cf = fmaxf(w_cobs[ch * H_ + j] + b_cobs[j], 0.f);
        bf16* r = feato + (size_t)row * 288;
        r[j]       = __float2bfloat16(tf * m);
        r[128 + j] = __float2bfloat16(cf * m);
        if (j == 0) r[256] = __float2bfloat16(xv * m);
        if (j < 31) r[257 + j] = __float2bfloat16(0.f);
    }
}

// ---------------------------------------------------------------------------
// All weight transposes (fp32 K x N -> bf16 N x Kp, zero pad k>=K) in 1 launch
// ---------------------------------------------------------------------------
struct WtArgs {
    const float* W[8];
    bf16* T[8];
    int K[8], Kp[8], N[8];
};
__global__ __launch_bounds__(288)
void wtrans_all_kernel(WtArgs a)
{
    const int i = blockIdx.y, n = blockIdx.x, k = threadIdx.x;
    if (n >= a.N[i] || k >= a.Kp[i]) return;
    a.T[i][(size_t)n * a.Kp[i] + k] =
        (k < a.K[i]) ? __float2bfloat16(a.W[i][(size_t)k * a.N[i] + n])
                     : __float2bfloat16(0.f);
}

// ---------------------------------------------------------------------------
// KV transpose v2: in (BH, L, H) -> out (BH, H, L). 32-row tiles,
// grid (L/32, BH) = 512 blocks, 256 thr.
// ---------------------------------------------------------------------------
__global__ __launch_bounds__(256)
void kvtrans_kernel(const bf16* __restrict__ in, bf16* __restrict__ out)
{
    __shared__ unsigned short tile[32 * 136];
    const int tid = threadIdx.x;
    const int l0 = blockIdx.x * 32;
    const int bh = blockIdx.y;
    const unsigned short* src = (const unsigned short*)(in + (size_t)bh * L_ * H_);
    unsigned short* dst = (unsigned short*)(out + (size_t)bh * H_ * L_);
    #pragma unroll
    for (int p = 0; p < 2; p++) {
        const int l = p * 16 + (tid >> 4);
        const int d0 = (tid & 15) * 8;
        *(uint4*)&tile[l * 136 + d0] = *(const uint4*)&src[(size_t)(l0 + l) * H_ + d0];
    }
    __syncthreads();
    const int d  = tid >> 1;
    const int lh = (tid & 1) * 16;
    unsigned short buf[16];
    #pragma unroll
    for (int j = 0; j < 16; j++) buf[j] = tile[(lh + j) * 136 + d];
    #pragma unroll
    for (int j = 0; j < 2; j++)
        *(uint4*)&dst[(size_t)d * L_ + l0 + lh + j * 8] = *(uint4*)&buf[j * 8];
}

// ---------------------------------------------------------------------------
// GEMM v3 (LDS stage-once, half-height tiles for occupancy):
// C = A(bf16 M x K) @ WT(bf16 N x K) + bias(fp32), optional bf16 residual R.
// Block = 128 thr = 2 waves, tile 32x64. ONE barrier, barrier-free MFMA loop.
// Grid (M/32, N/64). K multiple of 32, K <= 288.
// ---------------------------------------------------------------------------
__global__ __launch_bounds__(128)
void gemm_kernel(const bf16* __restrict__ A, const bf16* __restrict__ WT,
                 const float* __restrict__ bias, const bf16* __restrict__ R,
                 void* __restrict__ out, int K, int N, int mode, int do_relu)
{
    __shared__ __align__(16) unsigned short As[32 * 296];   // 18944 B max
    __shared__ __align__(16) unsigned short Ws[64 * 296];   // 37888 B max

    const int tid  = threadIdx.x;
    const int wave = tid >> 6, lane = tid & 63;
    const int quad = lane >> 4, l15 = lane & 15;
    const int m0 = blockIdx.x * 32;
    const int n0 = blockIdx.y * 64;
    const int Kp = K + 8;

    const int srow = tid >> 2;           // 0..31
    const int sc0  = (tid & 3) * 8;
    {
        const bf16* arow = A  + (size_t)(m0 + srow) * K;
        const bf16* w0   = WT + (size_t)(n0 + srow) * K;
        const bf16* w1   = WT + (size_t)(n0 + 32 + srow) * K;
        for (int col = sc0; col < K; col += 32) {
            *(uint4*)&As[srow * Kp + col]        = *(const uint4*)(arow + col);
            *(uint4*)&Ws[srow * Kp + col]        = *(const uint4*)(w0 + col);
            *(uint4*)&Ws[(32 + srow) * Kp + col] = *(const uint4*)(w1 + col);
        }
    }
    __syncthreads();

    f32x4 acc[4];
    #pragma unroll
    for (int c = 0; c < 4; c++) acc[c] = (f32x4){0.f, 0.f, 0.f, 0.f};

    const unsigned short* am = &As[(wave * 16 + l15) * Kp + quad * 8];
    #pragma unroll 4
    for (int kc = 0; kc < K; kc += 32) {
        bf16x8s af = *(const bf16x8s*)(am + kc);
        #pragma unroll
        for (int c = 0; c < 4; c++) {
            bf16x8s wf = *(const bf16x8s*)&Ws[(c * 16 + l15) * Kp + kc + quad * 8];
            acc[c] = __builtin_amdgcn_mfma_f32_16x16x32_bf16(af, wf, acc[c], 0, 0, 0);
        }
    }

    const int mw0 = m0 + wave * 16;
    #pragma unroll
    for (int c = 0; c < 4; c++) {
        const int n = n0 + c * 16 + l15;
        const float bv = bias[n];
        #pragma unroll
        for (int r = 0; r < 4; r++) {
            const int m = mw0 + quad * 4 + r;
            float v = acc[c][r] + bv;
            if (R != nullptr) v += __bfloat162float(R[(size_t)m * N + n]);
            if (do_relu) v = fmaxf(v, 0.f);
            if (mode == 0) {
                ((float*)out)[(size_t)m * N + n] = v;
            } else if (mode == 1) {
                ((bf16*)out)[(size_t)m * N + n] = __float2bfloat16(v);
            } else if (mode == 2) {
                const int b = m >> 11, l = m & 2047, hh = n >> 7, d = n & 127;
                ((bf16*)out)[(((size_t)(b * NH_ + hh)) * L_ + l) * H_ + d] = __float2bfloat16(v);
            } else {
                const int b = m >> 11, q = m & 2047, g = n >> 7, hh = n & 127;
                ((float*)out)[(((size_t)(b * G_ + g)) * L_ + q) * H_ + hh] = v;
            }
        }
    }
}

// ---------------------------------------------------------------------------
// Flash attention v7 (PROVEN, frozen). Canary: WRITE_SIZE >> 4 MB = pathology.
// ---------------------------------------------------------------------------
#define KT_S 136    // K tile row stride (shorts): 272 B, 16B-aligned
#define VT_S 72     // V^T tile row stride (shorts): 144 B, 16B-aligned
#define PS_S 72     // P row stride (shorts)

__global__ __launch_bounds__(512, 2)
void flash_attn_kernel(const bf16* __restrict__ Qb, const bf16* __restrict__ KVb,
                       const bf16* __restrict__ KVTb,
                       const float* __restrict__ mQ, const float* __restrict__ mK,
                       bf16* __restrict__ O)
{
    __shared__ __align__(16) char smem[90112];
    unsigned short* Ks = (unsigned short*)smem;
    unsigned short* Vs = (unsigned short*)(smem + 34816);
    unsigned short* Ps = (unsigned short*)(smem + 71680);
    float* Ocomb = (float*)smem;
    float* mcomb = (float*)(smem + 33792);
    float* lcomb = (float*)(smem + 34048);

    const int tid  = threadIdx.x;
    const int lane = tid & 63;
    const int wave = tid >> 6;         // 0..7
    const int half = wave >> 2;        // K-split half
    const int wq   = wave & 3;         // q sub-tile within block
    const int quad = lane >> 4;
    const int l15  = lane & 15;
    const int t256 = tid & 255;        // staging id within half
    const int bh = blockIdx.x, b = bh >> 1, h = bh & 1;
    const int q0 = blockIdx.y * 64;

    const bf16* kvb = KVb  + (size_t)bh * L_ * H_;
    const bf16* kvt = KVTb + (size_t)bh * H_ * L_;
    const float* mkb = mK + b * L_;

    const bf16* qrow = Qb + ((size_t)bh * L_ + q0 + wq * 16 + l15) * H_;
    bf16x8s qf[4];
    #pragma unroll
    for (int kc = 0; kc < 4; kc++)
        qf[kc] = *(const bf16x8s*)(qrow + kc * 32 + quad * 8);

    bool qz[4];
    #pragma unroll
    for (int r = 0; r < 4; r++)
        qz[r] = (mQ != nullptr) && (mQ[b * L_ + q0 + wq * 16 + quad * 4 + r] == 0.f);

    float mo[4], li[4];
    f32x4 Oacc[8];
    #pragma unroll
    for (int r = 0; r < 4; r++) { mo[r] = -1e30f; li[r] = 0.f; }
    #pragma unroll
    for (int c = 0; c < 8; c++) Oacc[c] = (f32x4){0.f, 0.f, 0.f, 0.f};

    const float SCALE = 0.08838834764831845f;    // 1/sqrt(128)
    unsigned short* KsH = Ks + half * 64 * KT_S;
    unsigned short* VsH = Vs + half * 128 * VT_S;
    unsigned short* pw  = Ps + wave * 16 * PS_S;

    const int krow_b = t256 >> 4, kcol = (t256 & 15) * 8;   // K: 16 thr/row
    const int vrow_b = t256 >> 3, vcol = (t256 & 7) * 8;    // V: 8 thr/row

    uint4 rk[4], rv[4];
    const int ks0 = half * 1024;

    {
        const int kb = ks0;
        #pragma unroll
        for (int p = 0; p < 4; p++)
            rk[p] = *(const uint4*)(kvb + (size_t)(kb + p * 16 + krow_b) * H_ + kcol);
        #pragma unroll
        for (int p = 0; p < 4; p++)
            rv[p] = *(const uint4*)(kvt + (size_t)(p * 32 + vrow_b) * L_ + kb + vcol);
        #pragma unroll
        for (int p = 0; p < 4; p++)
            *(uint4*)&KsH[(p * 16 + krow_b) * KT_S + kcol] = rk[p];
        #pragma unroll
        for (int p = 0; p < 4; p++)
            *(uint4*)&VsH[(p * 32 + vrow_b) * VT_S + vcol] = rv[p];
    }
    __syncthreads();

    for (int it = 0; it < 16; it++) {
        const int kb = ks0 + it * 64;

        if (it + 1 < 16) {
            const int kn = kb + 64;
            #pragma unroll
            for (int p = 0; p < 4; p++)
                rk[p] = *(const uint4*)(kvb + (size_t)(kn + p * 16 + krow_b) * H_ + kcol);
            #pragma unroll
            for (int p = 0; p < 4; p++)
                rv[p] = *(const uint4*)(kvt + (size_t)(p * 32 + vrow_b) * L_ + kn + vcol);
        }

        float koff[4];
        #pragma unroll
        for (int t = 0; t < 4; t++)
            koff[t] = (mkb[kb + t * 16 + l15] != 0.f) ? 0.f : -1000000.f;

        f32x4 sa[4];
        #pragma unroll
        for (int t = 0; t < 4; t++) sa[t] = (f32x4){0.f, 0.f, 0.f, 0.f};
        #pragma unroll
        for (int t = 0; t < 4; t++)
            #pragma unroll
            for (int kc = 0; kc < 4; kc++) {
                bf16x8s kf = *(const bf16x8s*)&KsH[(t * 16 + l15) * KT_S + kc * 32 + quad * 8];
                sa[t] = __builtin_amdgcn_mfma_f32_16x16x32_bf16(qf[kc], kf, sa[t], 0, 0, 0);
            }

        float s[4][4], mx[4];
        #pragma unroll
        for (int r = 0; r < 4; r++) {
            #pragma unroll
            for (int t = 0; t < 4; t++) {
                const float v = sa[t][r] * SCALE + koff[t];
                s[t][r] = qz[r] ? -1000000.f : v;   // exact -1e6 for masked queries
            }
            mx[r] = fmaxf(fmaxf(s[0][r], s[1][r]), fmaxf(s[2][r], s[3][r]));
        }
        #pragma unroll
        for (int off = 1; off < 16; off <<= 1)
            #pragma unroll
            for (int r = 0; r < 4; r++) mx[r] = fmaxf(mx[r], __shfl_xor(mx[r], off));

        float al[4], rs[4];
        #pragma unroll
        for (int r = 0; r < 4; r++) {
            const float mn = fmaxf(mo[r], mx[r]);
            al[r] = __expf(mo[r] - mn);
            mo[r] = mn;
            rs[r] = 0.f;
        }
        #pragma unroll
        for (int t = 0; t < 4; t++)
            #pragma unroll
            for (int r = 0; r < 4; r++) {
                const float p = __expf(s[t][r] - mo[r]);
                rs[r] += p;
                pw[(quad * 4 + r) * PS_S + t * 16 + l15] = f2bf_bits(p);
            }
        #pragma unroll
        for (int off = 1; off < 16; off <<= 1)
            #pragma unroll
            for (int r = 0; r < 4; r++) rs[r] += __shfl_xor(rs[r], off);
        #pragma unroll
        for (int r = 0; r < 4; r++) li[r] = li[r] * al[r] + rs[r];
        #pragma unroll
        for (int c = 0; c < 8; c++)
            #pragma unroll
            for (int r = 0; r < 4; r++) Oacc[c][r] *= al[r];

        bf16x8s pf0 = *(bf16x8s*)&pw[l15 * PS_S + quad * 8];
        bf16x8s pf1 = *(bf16x8s*)&pw[l15 * PS_S + 32 + quad * 8];

        #pragma unroll
        for (int c = 0; c < 8; c++) {
            bf16x8s v0 = *(const bf16x8s*)&VsH[(c * 16 + l15) * VT_S + quad * 8];
            bf16x8s v1 = *(const bf16x8s*)&VsH[(c * 16 + l15) * VT_S + 32 + quad * 8];
            Oacc[c] = __builtin_amdgcn_mfma_f32_16x16x32_bf16(pf0, v0, Oacc[c], 0, 0, 0);
            Oacc[c] = __builtin_amdgcn_mfma_f32_16x16x32_bf16(pf1, v1, Oacc[c], 0, 0, 0);
        }

        __syncthreads();                       // all waves done reading tiles
        if (it + 1 < 16) {
            #pragma unroll
            for (int p = 0; p < 4; p++)
                *(uint4*)&KsH[(p * 16 + krow_b) * KT_S + kcol] = rk[p];
            #pragma unroll
            for (int p = 0; p < 4; p++)
                *(uint4*)&VsH[(p * 32 + vrow_b) * VT_S + vcol] = rv[p];
            __syncthreads();
        }
    }

    if (half == 1) {
        #pragma unroll
        for (int c = 0; c < 8; c++)
            #pragma unroll
            for (int r = 0; r < 4; r++)
                Ocomb[(size_t)(wq * 16 + quad * 4 + r) * 132 + c * 16 + l15] = Oacc[c][r];
        if (l15 == 0) {
            #pragma unroll
            for (int r = 0; r < 4; r++) {
                mcomb[wq * 16 + quad * 4 + r] = mo[r];
                lcomb[wq * 16 + quad * 4 + r] = li[r];
            }
        }
    }
    __syncthreads();
    if (half == 0) {
        bf16* orow = O + ((size_t)b * L_ + q0 + wq * 16) * (NH_ * H_) + h * H_;
        #pragma unroll
        for (int r = 0; r < 4; r++) {
            const int row = quad * 4 + r;
            const float m1 = mcomb[wq * 16 + row];
            const float l1 = lcomb[wq * 16 + row];
            const float M  = fmaxf(mo[r], m1);
            const float a0 = __expf(mo[r] - M);
            const float a1 = __expf(m1 - M);
            const float inv = 1.f / (a0 * li[r] + a1 * l1);
            #pragma unroll
            for (int c = 0; c < 8; c++)
                orow[(size_t)row * (NH_ * H_) + c * 16 + l15] =
                    __float2bfloat16((a0 * Oacc[c][r] +
                                      a1 * Ocomb[(size_t)(wq * 16 + row) * 132 + c * 16 + l15]) * inv);
        }
    }
}

// ---------------------------------------------------------------------------
// qmw builder: mix_wt(10x128) @ ww_q(128x256) + b -> bf16 per-head (2,16,128)
// ---------------------------------------------------------------------------
__global__ __launch_bounds__(256)
void qmwb_kernel(const float* __restrict__ mixwt, const float* __restrict__ W,
                 const float* __restrict__ bias, bf16* __restrict__ qmwb)
{
    const int g = blockIdx.x;          // 0..15
    const int c = threadIdx.x;         // 0..255
    const int h = c >> 7, d = c & 127;
    if (g >= G_) { qmwb[((size_t)h * 16 + g) * 128 + d] = __float2bfloat16(0.f); return; }
    __shared__ float xr[128];
    if (c < 128) xr[c] = mixwt[g * 128 + c];
    __syncthreads();
    float acc = bias[c];
    #pragma unroll 8
    for (int i = 0; i < 128; i++)
        acc += xr[i] * W[i * 256 + c];
    qmwb[((size_t)h * 16 + g) * 128 + d] = __float2bfloat16(acc);
}

// ---------------------------------------------------------------------------
// mw partial attention v2: 32-way K-split (64-key tiles).
// grid (32, NH, B) = 256 blocks, 256 threads.
// ---------------------------------------------------------------------------
__global__ __launch_bounds__(256)
void mwpartial_kernel(const bf16* __restrict__ qmwb, const bf16* __restrict__ kvmw,
                      const float* __restrict__ mK,
                      float* __restrict__ mwO, float* __restrict__ mwM,
                      float* __restrict__ mwL)
{
    __shared__ __align__(16) unsigned short Ks[64 * 136];
    __shared__ float Qs[10 * 128];
    __shared__ float sc[10 * 64];
    __shared__ float mst[10], lst[10];

    const int tid = threadIdx.x;
    const int split = blockIdx.x, h = blockIdx.y, b = blockIdx.z;
    const int kbase = split * 64;
    const float SCALE = 0.08838834764831845f;

    for (int idx = tid; idx < 1280; idx += 256)
        Qs[idx] = __bfloat162float(qmwb[((size_t)h * 16 + (idx >> 7)) * 128 + (idx & 127)]);
    {
        const int rr = tid >> 2, qt = tid & 3;   // 64 rows, 4 thr/row
        const bf16* src = kvmw + (((size_t)(b * NH_ + h)) * L_ + kbase + rr) * H_ + qt * 32;
        #pragma unroll
        for (int i = 0; i < 4; i++)
            *(uint4*)(&Ks[rr * 136 + qt * 32 + i * 8]) = *(const uint4*)(src + i * 8);
    }
    __syncthreads();

    {
        const int j = tid & 63, qg = tid >> 6;   // key j, query-group qg 0..3
        float acc[3] = {0.f, 0.f, 0.f};
        for (int dc = 0; dc < 128; dc += 8) {
            bf16x8s kv = *(bf16x8s*)(&Ks[j * 136 + dc]);
            float kf[8];
            #pragma unroll
            for (int e = 0; e < 8; e++) kf[e] = us2f(((unsigned short*)&kv)[e]);
            #pragma unroll
            for (int qq = 0; qq < 3; qq++) {
                const int q = qg + 4 * qq;       // {qg, qg+4, qg+8}
                if (q < G_) {
                    const float* Qrow = &Qs[q * 128 + dc];
                    #pragma unroll
                    for (int e = 0; e < 8; e++) acc[qq] += Qrow[e] * kf[e];
                }
            }
        }
        const bool kz = (mK[b * L_ + kbase + j] == 0.f);
        #pragma unroll
        for (int qq = 0; qq < 3; qq++) {
            const int q = qg + 4 * qq;
            if (q < G_) sc[q * 64 + j] = kz ? -1000000.f : acc[qq] * SCALE;
        }
    }
    __syncthreads();
    if (tid < 160) {
        const int q = tid >> 4, t16 = tid & 15;
        float m = -3.4e38f;
        for (int jj = t16; jj < 64; jj += 16) m = fmaxf(m, sc[q * 64 + jj]);
        #pragma unroll
        for (int off = 1; off < 16; off <<= 1) m = fmaxf(m, __shfl_xor(m, off));
        if (t16 == 0) mst[q] = m;
    }
    __syncthreads();
    for (int idx = tid; idx < 640; idx += 256)
        sc[idx] = __expf(sc[idx] - mst[idx >> 6]);
    __syncthreads();
    if (tid < 160) {
        const int q = tid >> 4, t16 = tid & 15;
        float s = 0.f;
        for (int jj = t16; jj < 64; jj += 16) s += sc[q * 64 + jj];
        #pragma unroll
        for (int off = 1; off < 16; off <<= 1) s += __shfl_xor(s, off);
        if (t16 == 0) lst[q] = s;
    }
    __syncthreads();
    {
        const int d = tid & 127, qh = tid >> 7;  // 0..1, 5 queries each
        float acc[5] = {0.f, 0.f, 0.f, 0.f, 0.f};
        for (int jj = 0; jj < 64; jj++) {
            const float v = us2f(Ks[jj * 136 + d]);
            #pragma unroll
            for (int qq = 0; qq < 5; qq++)
                acc[qq] += sc[(qh * 5 + qq) * 64 + jj] * v;
        }
        const size_t base = ((size_t)(b * NH_ + h) * 32 + split) * 10;
        #pragma unroll
        for (int qq = 0; qq < 5; qq++)
            mwO[(base + qh * 5 + qq) * 128 + d] = acc[qq];
    }
    if (tid < 10) {
        const size_t base = ((size_t)(b * NH_ + h) * 32 + split) * 10;
        mwM[base + tid] = mst[tid];
        mwL[base + tid] = lst[tid];
    }
}

// ---------------------------------------------------------------------------
// mw proj v2 (parallelized tail part 1): grid (B, G) = 40 blocks, 256 thr.
// Each block: combine 32 K-splits for one (b,q) -> mwat[256] in LDS,
// project through ww_o (2-way split dot + LDS reduce) + mix_wt residual +
// ww_ob bias -> mwq[b][q][128] in global.
// Replaces the 4-block fused mwtail whose serial combine loop was 90 us.
// ---------------------------------------------------------------------------
__global__ __launch_bounds__(256)
void mwproj2_kernel(const float* __restrict__ mwO, const float* __restrict__ mwM,
                    const float* __restrict__ mwL, const float* __restrict__ mixwt,
                    const float* __restrict__ W, const float* __restrict__ bias,
                    float* __restrict__ mwq)
{
    __shared__ float mwat[256];
    __shared__ float part[256];

    const int b = blockIdx.x, q = blockIdx.y;
    const int tid = threadIdx.x;
    const int h = tid >> 7, d = tid & 127;

    // combine: thread tid owns column h*128+d
    const size_t hb = (size_t)(b * NH_ + h) * 32;
    float M = -3.4e38f;
    for (int s = 0; s < 32; s++) M = fmaxf(M, mwM[(hb + s) * 10 + q]);
    float l = 0.f, o = 0.f;
    for (int s = 0; s < 32; s++) {
        const float a = __expf(mwM[(hb + s) * 10 + q] - M);
        l += a * mwL[(hb + s) * 10 + q];
        o += a * mwO[((hb + s) * 10 + q) * 128 + d];
    }
    mwat[tid] = o / l;
    __syncthreads();

    // proj: output dim d2; 2 threads per output, each half of the 256-dot
    const int d2 = tid & 127, hf = tid >> 7;
    float acc = 0.f;
    #pragma unroll 8
    for (int i = hf * 128; i < hf * 128 + 128; i++)
        acc += mwat[i] * W[i * 128 + d2];
    part[tid] = acc;
    __syncthreads();
    if (tid < 128)
        mwq[((size_t)b * G_ + q) * 128 + tid] =
            mixwt[q * 128 + tid] + bias[tid] + part[tid] + part[128 + tid];
}

// mw final: z[q] = dot(mwq[b][q], wmix) + b ; softmax over q. grid B_, 64 thr.
__global__ __launch_bounds__(64)
void mwfinal_kernel(const float* __restrict__ MW, const float* __restrict__ wmix,
                    const float* __restrict__ bmix, float* __restrict__ out)
{
    const int b = blockIdx.x;
    const int g = threadIdx.x;
    __shared__ float z[16];
    if (g < G_) {
        float acc = bmix[0];
        for (int i = 0; i < 128; i++)
            acc += MW[((size_t)b * G_ + g) * 128 + i] * wmix[i];
        z[g] = acc;
    }
    __syncthreads();
    if (g == 0) {
        float mx = -3.4e38f;
        for (int i = 0; i < G_; i++) mx = fmaxf(mx, z[i]);
        float e[G_]; float s = 0.f;
        for (int i = 0; i < G_; i++) { e[i] = __expf(z[i] - mx); s += e[i]; }
        for (int i = 0; i < G_; i++) out[b * G_ + i] = e[i] / s;
    }
}

// ---------------------------------------------------------------------------
extern "C" void kernel_launch(void* const* d_in, const int* in_sizes, int n_in,
                              void* d_out, int out_size, void* d_ws, size_t ws_size,
                              hipStream_t stream)
{
    const float* obs    = (const float*)d_in[0];
    const float* mobs   = (const float*)d_in[1];
    const float* xq     = (const float*)d_in[2];
    const float* mq     = (const float*)d_in[3];
    const float* w_q0   = (const float*)d_in[4];
    const float* b_q0   = (const float*)d_in[5];
    const float* w_q1   = (const float*)d_in[6];
    const float* b_q1   = (const float*)d_in[7];
    const float* w_o0   = (const float*)d_in[8];
    const float* b_o0   = (const float*)d_in[9];
    const float* w_o1   = (const float*)d_in[10];
    const float* b_o1   = (const float*)d_in[11];
    const float* w_cobs = (const float*)d_in[12];
    const float* b_cobs = (const float*)d_in[13];
    const float* w_cq   = (const float*)d_in[14];
    const float* b_cq   = (const float*)d_in[15];
    const float* w_qp   = (const float*)d_in[16];
    const float* b_qp   = (const float*)d_in[17];
    const float* w_kp   = (const float*)d_in[18];
    const float* b_kp   = (const float*)d_in[19];
    const float* ws_q   = (const float*)d_in[20];
    const float* ws_qb  = (const float*)d_in[21];
    const float* ws_o   = (const float*)d_in[22];
    const float* ws_ob  = (const float*)d_in[23];
    const float* ww_q   = (const float*)d_in[24];
    const float* ww_qb  = (const float*)d_in[25];
    const float* ww_o   = (const float*)d_in[26];
    const float* ww_ob  = (const float*)d_in[27];
    const float* wc_q   = (const float*)d_in[28];
    const float* wc_qb  = (const float*)d_in[29];
    const float* wc_o   = (const float*)d_in[30];
    const float* wc_ob  = (const float*)d_in[31];
    const float* w_split= (const float*)d_in[32];
    const float* b_split= (const float*)d_in[33];
    const float* mix_wt = (const float*)d_in[34];
    const float* w_mix  = (const float*)d_in[35];
    const float* b_mix  = (const float*)d_in[36];

    float* out = (float*)d_out;
    char* ws  = (char*)d_ws;

    const size_t MB = (size_t)1 << 20;
    const size_t KB = (size_t)1 << 10;
    if (ws_size < 31 * MB) return;

    const int NROW = B_ * L_;          // 8192
    // layout (<=31 MB). qcb+kvcb and qe_bf+x_bf pairs MUST be contiguous.
    bf16* featq = (bf16*)(ws + 0);                 // 4 MB  -> kvbs, later qcb
    bf16* feato = (bf16*)(ws + 4 * MB);            // 4.5 MB -> later kvcb (at +4MB!)
    bf16* qe_bf = (bf16*)(ws + 8 * MB + 512 * KB); // 2 MB  \ contiguous pair
    bf16* x_bf  = (bf16*)(ws + 10 * MB + 512 * KB);// 2 MB  / for merged gemm
    bf16* oe_bf = (bf16*)(ws + 12 * MB + 512 * KB);// 2 MB
    bf16* abuf  = (bf16*)(ws + 14 * MB + 512 * KB);// 4 MB -> abuf2
    bf16* x2_bf = (bf16*)(ws + 18 * MB + 512 * KB);// 2 MB
    bf16* kvmw  = (bf16*)(ws + 20 * MB + 512 * KB);// 4 MB
    bf16* kvT   = (bf16*)(ws + 24 * MB + 512 * KB);// 4 MB (BH,H,L), self then cross
    char* wbase = ws + 28 * MB + 512 * KB;         // ~2.5 MB of weights/smalls
    bf16* wqpT  = (bf16*)(wbase + 0);              // 64 KB (128 x 256)
    bf16* wkpT  = (bf16*)(wbase + 64 * KB);        // 72 KB (128 x 288)
    bf16* wsqT  = (bf16*)(wbase + 136 * KB);       // 64 KB (256 x 128)
    bf16* wsoT  = (bf16*)(wbase + 200 * KB);       // 64 KB (128 x 256)
    bf16* wwqT  = (bf16*)(wbase + 264 * KB);       // 64 KB
    bf16* wcqT  = (bf16*)(wbase + 328 * KB);       // 64 KB
    bf16* wcoT  = (bf16*)(wbase + 392 * KB);       // 64 KB
    bf16* wsplT = (bf16*)(wbase + 456 * KB);       // 320 KB (1280 x 128)
    bf16* qmwb  = (bf16*)(wbase + 776 * KB);       // 8 KB (2,16,128)
    float* mwO  = (float*)(wbase + 784 * KB);      // 1280 KB (B,NH,32,10,128) fp32
    float* mwM  = (float*)(wbase + 2064 * KB);     // 10 KB
    float* mwL  = (float*)(wbase + 2080 * KB);     // 10 KB
    float* mwq  = (float*)(wbase + 2096 * KB);     // 20 KB (B,G,128) fp32
    bf16* kvbs  = featq;                           // self QKV (B,NH,L,H)
    bf16* qcb   = featq;                           // cross Q  (B,NH,L,H)
    bf16* kvcb  = (bf16*)(ws + 4 * MB);            // cross KV = qcb + 4MB
    bf16* abuf2 = abuf;

    // 0: all weight transposes in one launch
    WtArgs wa;
    wa.W[0]=w_qp;   wa.T[0]=wqpT;  wa.K[0]=256; wa.Kp[0]=256; wa.N[0]=128;
    wa.W[1]=w_kp;   wa.T[1]=wkpT;  wa.K[1]=257; wa.Kp[1]=288; wa.N[1]=128;
    wa.W[2]=ws_q;   wa.T[2]=wsqT;  wa.K[2]=128; wa.Kp[2]=128; wa.N[2]=256;
    wa.W[3]=ws_o;   wa.T[3]=wsoT;  wa.K[3]=256; wa.Kp[3]=256; wa.N[3]=128;
    wa.W[4]=ww_q;   wa.T[4]=wwqT;  wa.K[4]=128; wa.Kp[4]=128; wa.N[4]=256;
    wa.W[5]=wc_q;   wa.T[5]=wcqT;  wa.K[5]=128; wa.Kp[5]=128; wa.N[5]=256;
    wa.W[6]=wc_o;   wa.T[6]=wcoT;  wa.K[6]=256; wa.Kp[6]=256; wa.N[6]=128;
    wa.W[7]=w_split;wa.T[7]=wsplT; wa.K[7]=128; wa.Kp[7]=128; wa.N[7]=1280;
    wtrans_all_kernel<<<dim3(1280, 8), 288, 0, stream>>>(wa);

    // qmw query builder (depends only on inputs; fills pipeline gap early)
    qmwb_kernel<<<16, 256, 0, stream>>>(mix_wt, ww_q, ww_qb, qmwb);

    // 1-2: featurize (merged)
    featall_kernel<<<2 * NROW, 128, 0, stream>>>(xq, mq, obs, mobs,
                                                 w_q0, b_q0, w_q1, b_q1, w_cq, b_cq,
                                                 w_o0, b_o0, w_o1, b_o1, w_cobs, b_cobs,
                                                 featq, feato);
    // 3-4: embed projections (MFMA, 32x64-tile LDS gemm)
    gemm_kernel<<<dim3(NROW/32, 2), 128, 0, stream>>>(featq, wqpT, b_qp, nullptr,
                                                      qe_bf, 256, 128, 1, 0);
    gemm_kernel<<<dim3(NROW/32, 2), 128, 0, stream>>>(feato, wkpT, b_kp, nullptr,
                                                      oe_bf, 288, 128, 1, 0);
    // 5: self-attn shared q=k=v projection (per-head bf16) + transpose
    gemm_kernel<<<dim3(NROW/32, 4), 128, 0, stream>>>(oe_bf, wsqT, ws_qb, nullptr,
                                                      kvbs, 128, 256, 2, 0);
    kvtrans_kernel<<<dim3(L_/32, B_*NH_), 256, 0, stream>>>(kvbs, kvT);
    // 6: self attention (flash v7)
    flash_attn_kernel<<<dim3(B_*NH_, L_/64), 512, 0, stream>>>(kvbs, kvbs, kvT,
                                                               nullptr, mobs, abuf);
    // 7: x = relu(oe + attn @ ws_o + ws_ob)
    gemm_kernel<<<dim3(NROW/32, 2), 128, 0, stream>>>(abuf, wsoT, ws_ob, oe_bf,
                                                      x_bf, 256, 128, 1, 1);
    // 8-13: mixing-weights path
    gemm_kernel<<<dim3(NROW/32, 4), 128, 0, stream>>>(x_bf, wwqT, ww_qb, nullptr,
                                                      kvmw, 128, 256, 2, 0);
    mwpartial_kernel<<<dim3(32, NH_, B_), 256, 0, stream>>>(qmwb, kvmw, mobs,
                                                            mwO, mwM, mwL);
    mwproj2_kernel<<<dim3(B_, G_), 256, 0, stream>>>(mwO, mwM, mwL, mix_wt,
                                                     ww_o, ww_ob, mwq);
    mwfinal_kernel<<<B_, 64, 0, stream>>>(mwq, w_mix, b_mix,
                                          out + (size_t)B_ * G_ * L_ * H_);
    // 14: merged cross projections: [qe_bf; x_bf](16384x128) @ wc_q -> [qcb; kvcb]
    gemm_kernel<<<dim3(2*NROW/32, 4), 128, 0, stream>>>(qe_bf, wcqT, wc_qb, nullptr,
                                                        qcb, 128, 256, 2, 0);
    kvtrans_kernel<<<dim3(L_/32, B_*NH_), 256, 0, stream>>>(kvcb, kvT);
    // 16: cross attention
    flash_attn_kernel<<<dim3(B_*NH_, L_/64), 512, 0, stream>>>(qcb, kvcb, kvT,
                                                               mq, mobs, abuf2);
    // 17: x2 = relu(qe + attn2 @ wc_o + wc_ob)
    gemm_kernel<<<dim3(NROW/32, 2), 128, 0, stream>>>(abuf2, wcoT, wc_ob, qe_bf,
                                                      x2_bf, 256, 128, 1, 1);
    // 18: split + transpose store (MFMA)
    gemm_kernel<<<dim3(NROW/32, 20), 128, 0, stream>>>(x2_bf, wsplT, b_split, nullptr,
                                                       out, 128, 1280, 3, 0);

    (void)in_sizes; (void)n_in; (void)out_size;
}

// Round 14
// 430.114 us; speedup vs baseline: 1.2468x; 1.1421x over previous
//
#include <hip/hip_runtime.h>
#include <hip/hip_bf16.h>

#define B_  4
#define L_  2048      // LO == LQ == 2048
#define H_  128
#define NH_ 2
#define G_  10
#define NIN_ 41

typedef __hip_bfloat16 bf16;
typedef __attribute__((ext_vector_type(8))) short bf16x8s;  // 8 bf16 = 4 VGPRs
typedef __attribute__((ext_vector_type(4))) float f32x4;

__device__ __forceinline__ unsigned short f2bf_bits(float x) {
    __hip_bfloat16 h = __float2bfloat16(x);
    return *reinterpret_cast<unsigned short*>(&h);
}
__device__ __forceinline__ float us2f(unsigned short s) {
    return __uint_as_float(((unsigned int)s) << 16);
}

// ---------------------------------------------------------------------------
// K1+K2 merged: featurize query rows (blk < NROW) and obs rows (blk >= NROW)
// ---------------------------------------------------------------------------
__global__ __launch_bounds__(128)
void featall_kernel(const float* __restrict__ xq, const float* __restrict__ mq,
                    const float* __restrict__ obs, const float* __restrict__ mobs,
                    const float* __restrict__ w_q0, const float* __restrict__ b_q0,
                    const float* __restrict__ w_q1, const float* __restrict__ b_q1,
                    const float* __restrict__ w_cq, const float* __restrict__ b_cq,
                    const float* __restrict__ w_o0, const float* __restrict__ b_o0,
                    const float* __restrict__ w_o1, const float* __restrict__ b_o1,
                    const float* __restrict__ w_cobs, const float* __restrict__ b_cobs,
                    bf16* __restrict__ featq, bf16* __restrict__ feato)
{
    const int blk = blockIdx.x;
    const int j   = threadIdx.x;
    const int NROW = B_ * L_;
    if (blk < NROW) {
        const int row = blk;
        const float t   = xq[row * 2 + 0];
        const float chf = xq[row * 2 + 1];
        int ch = (int)chf; ch = max(0, min(NIN_ - 1, ch));
        const float m   = mq[row];
        float tf;
        if (j == 0) tf = t * w_q0[0] + b_q0[0];
        else        tf = __sinf(t * w_q1[j - 1] + b_q1[j - 1]);
        float cf = fmaxf(w_cq[ch * H_ + j] + b_cq[j], 0.f);
        featq[(size_t)row * 256 + j]       = __float2bfloat16(tf * m);
        featq[(size_t)row * 256 + 128 + j] = __float2bfloat16(cf * m);
    } else {
        const int row = blk - NROW;
        const float t   = obs[row * 3 + 0];
        const float chf = obs[row * 3 + 1];
        const float xv  = obs[row * 3 + 2];
        int ch = (int)chf; ch = max(0, min(NIN_ - 1, ch));
        const float m   = mobs[row];
        float tf;
        if (j == 0) tf = t * w_o0[0] + b_o0[0];
        else        tf = __sinf(t * w_o1[j - 1] + b_o1[j - 1]);
        float cf = fmaxf(w_cobs[ch * H_ + j] + b_cobs[j], 0.f);
        bf16* r = feato + (size_t)row * 288;
        r[j]       = __float2bfloat16(tf * m);
        r[128 + j] = __float2bfloat16(cf * m);
        if (j == 0) r[256] = __float2bfloat16(xv * m);
        if (j < 31) r[257 + j] = __float2bfloat16(0.f);
    }
}

// ---------------------------------------------------------------------------
// All weight transposes (fp32 K x N -> bf16 N x Kp, zero pad k>=K) in 1 launch
// ---------------------------------------------------------------------------
struct WtArgs {
    const float* W[8];
    bf16* T[8];
    int K[8], Kp[8], N[8];
};
__global__ __launch_bounds__(288)
void wtrans_all_kernel(WtArgs a)
{
    const int i = blockIdx.y, n = blockIdx.x, k = threadIdx.x;
    if (n >= a.N[i] || k >= a.Kp[i]) return;
    a.T[i][(size_t)n * a.Kp[i] + k] =
        (k < a.K[i]) ? __float2bfloat16(a.W[i][(size_t)k * a.N[i] + n])
                     : __float2bfloat16(0.f);
}

// ---------------------------------------------------------------------------
// KV transpose v2: in (BH, L, H) -> out (BH, H, L). 32-row tiles,
// grid (L/32, BH) = 512 blocks, 256 thr.
// ---------------------------------------------------------------------------
__global__ __launch_bounds__(256)
void kvtrans_kernel(const bf16* __restrict__ in, bf16* __restrict__ out)
{
    __shared__ unsigned short tile[32 * 136];
    const int tid = threadIdx.x;
    const int l0 = blockIdx.x * 32;
    const int bh = blockIdx.y;
    const unsigned short* src = (const unsigned short*)(in + (size_t)bh * L_ * H_);
    unsigned short* dst = (unsigned short*)(out + (size_t)bh * H_ * L_);
    #pragma unroll
    for (int p = 0; p < 2; p++) {
        const int l = p * 16 + (tid >> 4);
        const int d0 = (tid & 15) * 8;
        *(uint4*)&tile[l * 136 + d0] = *(const uint4*)&src[(size_t)(l0 + l) * H_ + d0];
    }
    __syncthreads();
    const int d  = tid >> 1;
    const int lh = (tid & 1) * 16;
    unsigned short buf[16];
    #pragma unroll
    for (int j = 0; j < 16; j++) buf[j] = tile[(lh + j) * 136 + d];
    #pragma unroll
    for (int j = 0; j < 2; j++)
        *(uint4*)&dst[(size_t)d * L_ + l0 + lh + j * 8] = *(uint4*)&buf[j * 8];
}

// ---------------------------------------------------------------------------
// GEMM v3 (LDS stage-once, half-height tiles for occupancy):
// C = A(bf16 M x K) @ WT(bf16 N x K) + bias(fp32), optional bf16 residual R.
// Block = 128 thr = 2 waves, tile 32x64. ONE barrier, barrier-free MFMA loop.
// Grid (M/32, N/64). K multiple of 32, K <= 288.
// ---------------------------------------------------------------------------
__global__ __launch_bounds__(128)
void gemm_kernel(const bf16* __restrict__ A, const bf16* __restrict__ WT,
                 const float* __restrict__ bias, const bf16* __restrict__ R,
                 void* __restrict__ out, int K, int N, int mode, int do_relu)
{
    __shared__ __align__(16) unsigned short As[32 * 296];   // 18944 B max
    __shared__ __align__(16) unsigned short Ws[64 * 296];   // 37888 B max

    const int tid  = threadIdx.x;
    const int wave = tid >> 6, lane = tid & 63;
    const int quad = lane >> 4, l15 = lane & 15;
    const int m0 = blockIdx.x * 32;
    const int n0 = blockIdx.y * 64;
    const int Kp = K + 8;

    const int srow = tid >> 2;           // 0..31
    const int sc0  = (tid & 3) * 8;
    {
        const bf16* arow = A  + (size_t)(m0 + srow) * K;
        const bf16* w0   = WT + (size_t)(n0 + srow) * K;
        const bf16* w1   = WT + (size_t)(n0 + 32 + srow) * K;
        for (int col = sc0; col < K; col += 32) {
            *(uint4*)&As[srow * Kp + col]        = *(const uint4*)(arow + col);
            *(uint4*)&Ws[srow * Kp + col]        = *(const uint4*)(w0 + col);
            *(uint4*)&Ws[(32 + srow) * Kp + col] = *(const uint4*)(w1 + col);
        }
    }
    __syncthreads();

    f32x4 acc[4];
    #pragma unroll
    for (int c = 0; c < 4; c++) acc[c] = (f32x4){0.f, 0.f, 0.f, 0.f};

    const unsigned short* am = &As[(wave * 16 + l15) * Kp + quad * 8];
    #pragma unroll 4
    for (int kc = 0; kc < K; kc += 32) {
        bf16x8s af = *(const bf16x8s*)(am + kc);
        #pragma unroll
        for (int c = 0; c < 4; c++) {
            bf16x8s wf = *(const bf16x8s*)&Ws[(c * 16 + l15) * Kp + kc + quad * 8];
            acc[c] = __builtin_amdgcn_mfma_f32_16x16x32_bf16(af, wf, acc[c], 0, 0, 0);
        }
    }

    const int mw0 = m0 + wave * 16;
    #pragma unroll
    for (int c = 0; c < 4; c++) {
        const int n = n0 + c * 16 + l15;
        const float bv = bias[n];
        #pragma unroll
        for (int r = 0; r < 4; r++) {
            const int m = mw0 + quad * 4 + r;
            float v = acc[c][r] + bv;
            if (R != nullptr) v += __bfloat162float(R[(size_t)m * N + n]);
            if (do_relu) v = fmaxf(v, 0.f);
            if (mode == 0) {
                ((float*)out)[(size_t)m * N + n] = v;
            } else if (mode == 1) {
                ((bf16*)out)[(size_t)m * N + n] = __float2bfloat16(v);
            } else if (mode == 2) {
                const int b = m >> 11, l = m & 2047, hh = n >> 7, d = n & 127;
                ((bf16*)out)[(((size_t)(b * NH_ + hh)) * L_ + l) * H_ + d] = __float2bfloat16(v);
            } else {
                const int b = m >> 11, q = m & 2047, g = n >> 7, hh = n & 127;
                ((float*)out)[(((size_t)(b * G_ + g)) * L_ + q) * H_ + hh] = v;
            }
        }
    }
}

// ---------------------------------------------------------------------------
// Flash attention v13: 256 thr = 4 waves = 2 q-subtiles (16 rows) x 2-way
// K-split, QBLK=32, NO register prefetch: per tile, stage = load->store
// inside the barrier window (zero regs held across the MFMA region -> live
// state strictly BELOW the proven v7; r8's pathology came from rk[8]/rv[8]
// held across compute). LDS = 34816(K) + 36864(V) + 9216(P) = 80896 B
// -> TWO blocks/CU: the co-resident block's compute hides our staging.
// Grid (bh=8, L/32=64) = 512 blocks; bh fastest -> per-XCD KV L2 affinity.
// Combine path byte-identical to the correctness-verified r8 version.
// Canary: WRITE_SIZE >> 4 MB = compiler scratch pathology -> revert to v7.
// ---------------------------------------------------------------------------
#define KT_S 136    // K tile row stride (shorts): 272 B, 16B-aligned
#define VT_S 72     // V^T tile row stride (shorts): 144 B, 16B-aligned
#define PS_S 72     // P row stride (shorts)

__global__ __launch_bounds__(256, 2)
void flash_attn_kernel(const bf16* __restrict__ Qb, const bf16* __restrict__ KVb,
                       const bf16* __restrict__ KVTb,
                       const float* __restrict__ mQ, const float* __restrict__ mK,
                       bf16* __restrict__ O)
{
    // Ks [2][64][136] = 34816 B | Vs [2][128][72] = 36864 B
    // Ps [4][16][72]  =  9216 B  -> 80896 B total
    // Combine (aliased post-barrier): Ocomb 32*132*4 = 16896 B,
    //   mcomb @16896 (128 B), lcomb @17024 (128 B)
    __shared__ __align__(16) char smem[80896];
    unsigned short* Ks = (unsigned short*)smem;
    unsigned short* Vs = (unsigned short*)(smem + 34816);
    unsigned short* Ps = (unsigned short*)(smem + 71680);
    float* Ocomb = (float*)smem;
    float* mcomb = (float*)(smem + 16896);
    float* lcomb = (float*)(smem + 17024);

    const int tid  = threadIdx.x;
    const int lane = tid & 63;
    const int wave = tid >> 6;         // 0..3
    const int half = wave >> 1;        // K-split half
    const int wq   = wave & 1;         // q sub-tile within block (16 rows)
    const int quad = lane >> 4;
    const int l15  = lane & 15;
    const int t128 = tid & 127;        // staging id within half
    const int bh = blockIdx.x, b = bh >> 1, h = bh & 1;
    const int q0 = blockIdx.y * 32;

    const bf16* kvb = KVb  + (size_t)bh * L_ * H_;
    const bf16* kvt = KVTb + (size_t)bh * H_ * L_;
    const float* mkb = mK + b * L_;

    // ---- Q fragments (16 q-rows per wave, from global, once) ----
    const bf16* qrow = Qb + ((size_t)bh * L_ + q0 + wq * 16 + l15) * H_;
    bf16x8s qf[4];
    #pragma unroll
    for (int kc = 0; kc < 4; kc++)
        qf[kc] = *(const bf16x8s*)(qrow + kc * 32 + quad * 8);

    bool qz[4];
    #pragma unroll
    for (int r = 0; r < 4; r++)
        qz[r] = (mQ != nullptr) && (mQ[b * L_ + q0 + wq * 16 + quad * 4 + r] == 0.f);

    float mo[4], li[4];
    f32x4 Oacc[8];
    #pragma unroll
    for (int r = 0; r < 4; r++) { mo[r] = -1e30f; li[r] = 0.f; }
    #pragma unroll
    for (int c = 0; c < 8; c++) Oacc[c] = (f32x4){0.f, 0.f, 0.f, 0.f};

    const float SCALE = 0.08838834764831845f;    // 1/sqrt(128)
    unsigned short* KsH = Ks + half * 64 * KT_S;
    unsigned short* VsH = Vs + half * 128 * VT_S;
    unsigned short* pw  = Ps + wave * 16 * PS_S;

    // staging geometry (within the 128-thread half):
    // K: rows krow_b + 8p (p<8), 16 thr/row; V: rows vrow_b + 16p, 8 thr/row
    const int krow_b = t128 >> 4, kcol = (t128 & 15) * 8;
    const int vrow_b = t128 >> 3, vcol = (t128 & 7) * 8;

    const int ks0 = half * 1024;

    // ---- stage tile 0 (load->store, nothing held afterwards) ----
    {
        const int kb = ks0;
        uint4 t0[8];
        #pragma unroll
        for (int p = 0; p < 8; p++)
            t0[p] = *(const uint4*)(kvb + (size_t)(kb + p * 8 + krow_b) * H_ + kcol);
        #pragma unroll
        for (int p = 0; p < 8; p++)
            *(uint4*)&KsH[(p * 8 + krow_b) * KT_S + kcol] = t0[p];
        #pragma unroll
        for (int p = 0; p < 8; p++)
            t0[p] = *(const uint4*)(kvt + (size_t)(p * 16 + vrow_b) * L_ + kb + vcol);
        #pragma unroll
        for (int p = 0; p < 8; p++)
            *(uint4*)&VsH[(p * 16 + vrow_b) * VT_S + vcol] = t0[p];
    }
    __syncthreads();

    for (int it = 0; it < 16; it++) {
        const int kb = ks0 + it * 64;

        // ---- k-mask as additive offset ----
        float koff[4];
        #pragma unroll
        for (int t = 0; t < 4; t++)
            koff[t] = (mkb[kb + t * 16 + l15] != 0.f) ? 0.f : -1000000.f;

        // ---- S = Q K^T over 4 16-key sub-tiles (K-frags from LDS) ----
        f32x4 sa[4];
        #pragma unroll
        for (int t = 0; t < 4; t++) sa[t] = (f32x4){0.f, 0.f, 0.f, 0.f};
        #pragma unroll
        for (int t = 0; t < 4; t++)
            #pragma unroll
            for (int kc = 0; kc < 4; kc++) {
                bf16x8s kf = *(const bf16x8s*)&KsH[(t * 16 + l15) * KT_S + kc * 32 + quad * 8];
                sa[t] = __builtin_amdgcn_mfma_f32_16x16x32_bf16(qf[kc], kf, sa[t], 0, 0, 0);
            }

        // ---- mask + online softmax over 64 keys ----
        float s[4][4], mx[4];
        #pragma unroll
        for (int r = 0; r < 4; r++) {
            #pragma unroll
            for (int t = 0; t < 4; t++) {
                const float v = sa[t][r] * SCALE + koff[t];
                s[t][r] = qz[r] ? -1000000.f : v;   // exact -1e6 for masked queries
            }
            mx[r] = fmaxf(fmaxf(s[0][r], s[1][r]), fmaxf(s[2][r], s[3][r]));
        }
        #pragma unroll
        for (int off = 1; off < 16; off <<= 1)
            #pragma unroll
            for (int r = 0; r < 4; r++) mx[r] = fmaxf(mx[r], __shfl_xor(mx[r], off));

        float al[4], rs[4];
        #pragma unroll
        for (int r = 0; r < 4; r++) {
            const float mn = fmaxf(mo[r], mx[r]);
            al[r] = __expf(mo[r] - mn);
            mo[r] = mn;
            rs[r] = 0.f;
        }
        #pragma unroll
        for (int t = 0; t < 4; t++)
            #pragma unroll
            for (int r = 0; r < 4; r++) {
                const float p = __expf(s[t][r] - mo[r]);
                rs[r] += p;
                pw[(quad * 4 + r) * PS_S + t * 16 + l15] = f2bf_bits(p);
            }
        #pragma unroll
        for (int off = 1; off < 16; off <<= 1)
            #pragma unroll
            for (int r = 0; r < 4; r++) rs[r] += __shfl_xor(rs[r], off);
        #pragma unroll
        for (int r = 0; r < 4; r++) li[r] = li[r] * al[r] + rs[r];
        #pragma unroll
        for (int c = 0; c < 8; c++)
            #pragma unroll
            for (int r = 0; r < 4; r++) Oacc[c][r] *= al[r];

        // ---- P A-frags (wave-private LDS round trip) ----
        bf16x8s pf0 = *(bf16x8s*)&pw[l15 * PS_S + quad * 8];
        bf16x8s pf1 = *(bf16x8s*)&pw[l15 * PS_S + 32 + quad * 8];

        // ---- O += P V (V^T frags from LDS) ----
        #pragma unroll
        for (int c = 0; c < 8; c++) {
            bf16x8s v0 = *(const bf16x8s*)&VsH[(c * 16 + l15) * VT_S + quad * 8];
            bf16x8s v1 = *(const bf16x8s*)&VsH[(c * 16 + l15) * VT_S + 32 + quad * 8];
            Oacc[c] = __builtin_amdgcn_mfma_f32_16x16x32_bf16(pf0, v0, Oacc[c], 0, 0, 0);
            Oacc[c] = __builtin_amdgcn_mfma_f32_16x16x32_bf16(pf1, v1, Oacc[c], 0, 0, 0);
        }

        // ---- stage next tile (load->store inside the barrier window) ----
        __syncthreads();                       // all waves done reading tiles
        if (it + 1 < 16) {
            const int kn = kb + 64;
            uint4 t0[8];
            #pragma unroll
            for (int p = 0; p < 8; p++)
                t0[p] = *(const uint4*)(kvb + (size_t)(kn + p * 8 + krow_b) * H_ + kcol);
            #pragma unroll
            for (int p = 0; p < 8; p++)
                *(uint4*)&KsH[(p * 8 + krow_b) * KT_S + kcol] = t0[p];
            #pragma unroll
            for (int p = 0; p < 8; p++)
                t0[p] = *(const uint4*)(kvt + (size_t)(p * 16 + vrow_b) * L_ + kn + vcol);
            #pragma unroll
            for (int p = 0; p < 8; p++)
                *(uint4*)&VsH[(p * 16 + vrow_b) * VT_S + vcol] = t0[p];
            __syncthreads();
        }
    }

    // ---- 2-way K-split combine (Ocomb aliases the tiles, post-barrier) ----
    if (half == 1) {
        #pragma unroll
        for (int c = 0; c < 8; c++)
            #pragma unroll
            for (int r = 0; r < 4; r++)
                Ocomb[(size_t)(wq * 16 + quad * 4 + r) * 132 + c * 16 + l15] = Oacc[c][r];
        if (l15 == 0) {
            #pragma unroll
            for (int r = 0; r < 4; r++) {
                mcomb[wq * 16 + quad * 4 + r] = mo[r];
                lcomb[wq * 16 + quad * 4 + r] = li[r];
            }
        }
    }
    __syncthreads();
    if (half == 0) {
        bf16* orow = O + ((size_t)b * L_ + q0 + wq * 16) * (NH_ * H_) + h * H_;
        #pragma unroll
        for (int r = 0; r < 4; r++) {
            const int row = quad * 4 + r;
            const float m1 = mcomb[wq * 16 + row];
            const float l1 = lcomb[wq * 16 + row];
            const float M  = fmaxf(mo[r], m1);
            const float a0 = __expf(mo[r] - M);
            const float a1 = __expf(m1 - M);
            const float inv = 1.f / (a0 * li[r] + a1 * l1);
            #pragma unroll
            for (int c = 0; c < 8; c++)
                orow[(size_t)row * (NH_ * H_) + c * 16 + l15] =
                    __float2bfloat16((a0 * Oacc[c][r] +
                                      a1 * Ocomb[(size_t)(wq * 16 + row) * 132 + c * 16 + l15]) * inv);
        }
    }
}

// ---------------------------------------------------------------------------
// qmw builder: mix_wt(10x128) @ ww_q(128x256) + b -> bf16 per-head (2,16,128)
// ---------------------------------------------------------------------------
__global__ __launch_bounds__(256)
void qmwb_kernel(const float* __restrict__ mixwt, const float* __restrict__ W,
                 const float* __restrict__ bias, bf16* __restrict__ qmwb)
{
    const int g = blockIdx.x;          // 0..15
    const int c = threadIdx.x;         // 0..255
    const int h = c >> 7, d = c & 127;
    if (g >= G_) { qmwb[((size_t)h * 16 + g) * 128 + d] = __float2bfloat16(0.f); return; }
    __shared__ float xr[128];
    if (c < 128) xr[c] = mixwt[g * 128 + c];
    __syncthreads();
    float acc = bias[c];
    #pragma unroll 8
    for (int i = 0; i < 128; i++)
        acc += xr[i] * W[i * 256 + c];
    qmwb[((size_t)h * 16 + g) * 128 + d] = __float2bfloat16(acc);
}

// ---------------------------------------------------------------------------
// mw partial attention v2: 32-way K-split (64-key tiles).
// grid (32, NH, B) = 256 blocks, 256 threads.
// ---------------------------------------------------------------------------
__global__ __launch_bounds__(256)
void mwpartial_kernel(const bf16* __restrict__ qmwb, const bf16* __restrict__ kvmw,
                      const float* __restrict__ mK,
                      float* __restrict__ mwO, float* __restrict__ mwM,
                      float* __restrict__ mwL)
{
    __shared__ __align__(16) unsigned short Ks[64 * 136];
    __shared__ float Qs[10 * 128];
    __shared__ float sc[10 * 64];
    __shared__ float mst[10], lst[10];

    const int tid = threadIdx.x;
    const int split = blockIdx.x, h = blockIdx.y, b = blockIdx.z;
    const int kbase = split * 64;
    const float SCALE = 0.08838834764831845f;

    for (int idx = tid; idx < 1280; idx += 256)
        Qs[idx] = __bfloat162float(qmwb[((size_t)h * 16 + (idx >> 7)) * 128 + (idx & 127)]);
    {
        const int rr = tid >> 2, qt = tid & 3;   // 64 rows, 4 thr/row
        const bf16* src = kvmw + (((size_t)(b * NH_ + h)) * L_ + kbase + rr) * H_ + qt * 32;
        #pragma unroll
        for (int i = 0; i < 4; i++)
            *(uint4*)(&Ks[rr * 136 + qt * 32 + i * 8]) = *(const uint4*)(src + i * 8);
    }
    __syncthreads();

    {
        const int j = tid & 63, qg = tid >> 6;   // key j, query-group qg 0..3
        float acc[3] = {0.f, 0.f, 0.f};
        for (int dc = 0; dc < 128; dc += 8) {
            bf16x8s kv = *(bf16x8s*)(&Ks[j * 136 + dc]);
            float kf[8];
            #pragma unroll
            for (int e = 0; e < 8; e++) kf[e] = us2f(((unsigned short*)&kv)[e]);
            #pragma unroll
            for (int qq = 0; qq < 3; qq++) {
                const int q = qg + 4 * qq;       // {qg, qg+4, qg+8}
                if (q < G_) {
                    const float* Qrow = &Qs[q * 128 + dc];
                    #pragma unroll
                    for (int e = 0; e < 8; e++) acc[qq] += Qrow[e] * kf[e];
                }
            }
        }
        const bool kz = (mK[b * L_ + kbase + j] == 0.f);
        #pragma unroll
        for (int qq = 0; qq < 3; qq++) {
            const int q = qg + 4 * qq;
            if (q < G_) sc[q * 64 + j] = kz ? -1000000.f : acc[qq] * SCALE;
        }
    }
    __syncthreads();
    if (tid < 160) {
        const int q = tid >> 4, t16 = tid & 15;
        float m = -3.4e38f;
        for (int jj = t16; jj < 64; jj += 16) m = fmaxf(m, sc[q * 64 + jj]);
        #pragma unroll
        for (int off = 1; off < 16; off <<= 1) m = fmaxf(m, __shfl_xor(m, off));
        if (t16 == 0) mst[q] = m;
    }
    __syncthreads();
    for (int idx = tid; idx < 640; idx += 256)
        sc[idx] = __expf(sc[idx] - mst[idx >> 6]);
    __syncthreads();
    if (tid < 160) {
        const int q = tid >> 4, t16 = tid & 15;
        float s = 0.f;
        for (int jj = t16; jj < 64; jj += 16) s += sc[q * 64 + jj];
        #pragma unroll
        for (int off = 1; off < 16; off <<= 1) s += __shfl_xor(s, off);
        if (t16 == 0) lst[q] = s;
    }
    __syncthreads();
    {
        const int d = tid & 127, qh = tid >> 7;  // 0..1, 5 queries each
        float acc[5] = {0.f, 0.f, 0.f, 0.f, 0.f};
        for (int jj = 0; jj < 64; jj++) {
            const float v = us2f(Ks[jj * 136 + d]);
            #pragma unroll
            for (int qq = 0; qq < 5; qq++)
                acc[qq] += sc[(qh * 5 + qq) * 64 + jj] * v;
        }
        const size_t base = ((size_t)(b * NH_ + h) * 32 + split) * 10;
        #pragma unroll
        for (int qq = 0; qq < 5; qq++)
            mwO[(base + qh * 5 + qq) * 128 + d] = acc[qq];
    }
    if (tid < 10) {
        const size_t base = ((size_t)(b * NH_ + h) * 32 + split) * 10;
        mwM[base + tid] = mst[tid];
        mwL[base + tid] = lst[tid];
    }
}

// ---------------------------------------------------------------------------
// mw proj v2 (parallelized tail part 1): grid (B, G) = 40 blocks, 256 thr.
// ---------------------------------------------------------------------------
__global__ __launch_bounds__(256)
void mwproj2_kernel(const float* __restrict__ mwO, const float* __restrict__ mwM,
                    const float* __restrict__ mwL, const float* __restrict__ mixwt,
                    const float* __restrict__ W, const float* __restrict__ bias,
                    float* __restrict__ mwq)
{
    __shared__ float mwat[256];
    __shared__ float part[256];

    const int b = blockIdx.x, q = blockIdx.y;
    const int tid = threadIdx.x;
    const int h = tid >> 7, d = tid & 127;

    // combine: thread tid owns column h*128+d
    const size_t hb = (size_t)(b * NH_ + h) * 32;
    float M = -3.4e38f;
    for (int s = 0; s < 32; s++) M = fmaxf(M, mwM[(hb + s) * 10 + q]);
    float l = 0.f, o = 0.f;
    for (int s = 0; s < 32; s++) {
        const float a = __expf(mwM[(hb + s) * 10 + q] - M);
        l += a * mwL[(hb + s) * 10 + q];
        o += a * mwO[((hb + s) * 10 + q) * 128 + d];
    }
    mwat[tid] = o / l;
    __syncthreads();

    // proj: output dim d2; 2 threads per output, each half of the 256-dot
    const int d2 = tid & 127, hf = tid >> 7;
    float acc = 0.f;
    #pragma unroll 8
    for (int i = hf * 128; i < hf * 128 + 128; i++)
        acc += mwat[i] * W[i * 128 + d2];
    part[tid] = acc;
    __syncthreads();
    if (tid < 128)
        mwq[((size_t)b * G_ + q) * 128 + tid] =
            mixwt[q * 128 + tid] + bias[tid] + part[tid] + part[128 + tid];
}

// mw final: z[q] = dot(mwq[b][q], wmix) + b ; softmax over q. grid B_, 64 thr.
__global__ __launch_bounds__(64)
void mwfinal_kernel(const float* __restrict__ MW, const float* __restrict__ wmix,
                    const float* __restrict__ bmix, float* __restrict__ out)
{
    const int b = blockIdx.x;
    const int g = threadIdx.x;
    __shared__ float z[16];
    if (g < G_) {
        float acc = bmix[0];
        for (int i = 0; i < 128; i++)
            acc += MW[((size_t)b * G_ + g) * 128 + i] * wmix[i];
        z[g] = acc;
    }
    __syncthreads();
    if (g == 0) {
        float mx = -3.4e38f;
        for (int i = 0; i < G_; i++) mx = fmaxf(mx, z[i]);
        float e[G_]; float s = 0.f;
        for (int i = 0; i < G_; i++) { e[i] = __expf(z[i] - mx); s += e[i]; }
        for (int i = 0; i < G_; i++) out[b * G_ + i] = e[i] / s;
    }
}

// ---------------------------------------------------------------------------
extern "C" void kernel_launch(void* const* d_in, const int* in_sizes, int n_in,
                              void* d_out, int out_size, void* d_ws, size_t ws_size,
                              hipStream_t stream)
{
    const float* obs    = (const float*)d_in[0];
    const float* mobs   = (const float*)d_in[1];
    const float* xq     = (const float*)d_in[2];
    const float* mq     = (const float*)d_in[3];
    const float* w_q0   = (const float*)d_in[4];
    const float* b_q0   = (const float*)d_in[5];
    const float* w_q1   = (const float*)d_in[6];
    const float* b_q1   = (const float*)d_in[7];
    const float* w_o0   = (const float*)d_in[8];
    const float* b_o0   = (const float*)d_in[9];
    const float* w_o1   = (const float*)d_in[10];
    const float* b_o1   = (const float*)d_in[11];
    const float* w_cobs = (const float*)d_in[12];
    const float* b_cobs = (const float*)d_in[13];
    const float* w_cq   = (const float*)d_in[14];
    const float* b_cq   = (const float*)d_in[15];
    const float* w_qp   = (const float*)d_in[16];
    const float* b_qp   = (const float*)d_in[17];
    const float* w_kp   = (const float*)d_in[18];
    const float* b_kp   = (const float*)d_in[19];
    const float* ws_q   = (const float*)d_in[20];
    const float* ws_qb  = (const float*)d_in[21];
    const float* ws_o   = (const float*)d_in[22];
    const float* ws_ob  = (const float*)d_in[23];
    const float* ww_q   = (const float*)d_in[24];
    const float* ww_qb  = (const float*)d_in[25];
    const float* ww_o   = (const float*)d_in[26];
    const float* ww_ob  = (const float*)d_in[27];
    const float* wc_q   = (const float*)d_in[28];
    const float* wc_qb  = (const float*)d_in[29];
    const float* wc_o   = (const float*)d_in[30];
    const float* wc_ob  = (const float*)d_in[31];
    const float* w_split= (const float*)d_in[32];
    const float* b_split= (const float*)d_in[33];
    const float* mix_wt = (const float*)d_in[34];
    const float* w_mix  = (const float*)d_in[35];
    const float* b_mix  = (const float*)d_in[36];

    float* out = (float*)d_out;
    char* ws  = (char*)d_ws;

    const size_t MB = (size_t)1 << 20;
    const size_t KB = (size_t)1 << 10;
    if (ws_size < 31 * MB) return;

    const int NROW = B_ * L_;          // 8192
    // layout (<=31 MB). qcb+kvcb and qe_bf+x_bf pairs MUST be contiguous.
    bf16* featq = (bf16*)(ws + 0);                 // 4 MB  -> kvbs, later qcb
    bf16* feato = (bf16*)(ws + 4 * MB);            // 4.5 MB -> later kvcb (at +4MB!)
    bf16* qe_bf = (bf16*)(ws + 8 * MB + 512 * KB); // 2 MB  \ contiguous pair
    bf16* x_bf  = (bf16*)(ws + 10 * MB + 512 * KB);// 2 MB  / for merged gemm
    bf16* oe_bf = (bf16*)(ws + 12 * MB + 512 * KB);// 2 MB
    bf16* abuf  = (bf16*)(ws + 14 * MB + 512 * KB);// 4 MB -> abuf2
    bf16* x2_bf = (bf16*)(ws + 18 * MB + 512 * KB);// 2 MB
    bf16* kvmw  = (bf16*)(ws + 20 * MB + 512 * KB);// 4 MB
    bf16* kvT   = (bf16*)(ws + 24 * MB + 512 * KB);// 4 MB (BH,H,L), self then cross
    char* wbase = ws + 28 * MB + 512 * KB;         // ~2.5 MB of weights/smalls
    bf16* wqpT  = (bf16*)(wbase + 0);              // 64 KB (128 x 256)
    bf16* wkpT  = (bf16*)(wbase + 64 * KB);        // 72 KB (128 x 288)
    bf16* wsqT  = (bf16*)(wbase + 136 * KB);       // 64 KB (256 x 128)
    bf16* wsoT  = (bf16*)(wbase + 200 * KB);       // 64 KB (128 x 256)
    bf16* wwqT  = (bf16*)(wbase + 264 * KB);       // 64 KB
    bf16* wcqT  = (bf16*)(wbase + 328 * KB);       // 64 KB
    bf16* wcoT  = (bf16*)(wbase + 392 * KB);       // 64 KB
    bf16* wsplT = (bf16*)(wbase + 456 * KB);       // 320 KB (1280 x 128)
    bf16* qmwb  = (bf16*)(wbase + 776 * KB);       // 8 KB (2,16,128)
    float* mwO  = (float*)(wbase + 784 * KB);      // 1280 KB (B,NH,32,10,128) fp32
    float* mwM  = (float*)(wbase + 2064 * KB);     // 10 KB
    float* mwL  = (float*)(wbase + 2080 * KB);     // 10 KB
    float* mwq  = (float*)(wbase + 2096 * KB);     // 20 KB (B,G,128) fp32
    bf16* kvbs  = featq;                           // self QKV (B,NH,L,H)
    bf16* qcb   = featq;                           // cross Q  (B,NH,L,H)
    bf16* kvcb  = (bf16*)(ws + 4 * MB);            // cross KV = qcb + 4MB
    bf16* abuf2 = abuf;

    // 0: all weight transposes in one launch
    WtArgs wa;
    wa.W[0]=w_qp;   wa.T[0]=wqpT;  wa.K[0]=256; wa.Kp[0]=256; wa.N[0]=128;
    wa.W[1]=w_kp;   wa.T[1]=wkpT;  wa.K[1]=257; wa.Kp[1]=288; wa.N[1]=128;
    wa.W[2]=ws_q;   wa.T[2]=wsqT;  wa.K[2]=128; wa.Kp[2]=128; wa.N[2]=256;
    wa.W[3]=ws_o;   wa.T[3]=wsoT;  wa.K[3]=256; wa.Kp[3]=256; wa.N[3]=128;
    wa.W[4]=ww_q;   wa.T[4]=wwqT;  wa.K[4]=128; wa.Kp[4]=128; wa.N[4]=256;
    wa.W[5]=wc_q;   wa.T[5]=wcqT;  wa.K[5]=128; wa.Kp[5]=128; wa.N[5]=256;
    wa.W[6]=wc_o;   wa.T[6]=wcoT;  wa.K[6]=256; wa.Kp[6]=256; wa.N[6]=128;
    wa.W[7]=w_split;wa.T[7]=wsplT; wa.K[7]=128; wa.Kp[7]=128; wa.N[7]=1280;
    wtrans_all_kernel<<<dim3(1280, 8), 288, 0, stream>>>(wa);

    // qmw query builder (depends only on inputs; fills pipeline gap early)
    qmwb_kernel<<<16, 256, 0, stream>>>(mix_wt, ww_q, ww_qb, qmwb);

    // 1-2: featurize (merged)
    featall_kernel<<<2 * NROW, 128, 0, stream>>>(xq, mq, obs, mobs,
                                                 w_q0, b_q0, w_q1, b_q1, w_cq, b_cq,
                                                 w_o0, b_o0, w_o1, b_o1, w_cobs, b_cobs,
                                                 featq, feato);
    // 3-4: embed projections (MFMA, 32x64-tile LDS gemm)
    gemm_kernel<<<dim3(NROW/32, 2), 128, 0, stream>>>(featq, wqpT, b_qp, nullptr,
                                                      qe_bf, 256, 128, 1, 0);
    gemm_kernel<<<dim3(NROW/32, 2), 128, 0, stream>>>(feato, wkpT, b_kp, nullptr,
                                                      oe_bf, 288, 128, 1, 0);
    // 5: self-attn shared q=k=v projection (per-head bf16) + transpose
    gemm_kernel<<<dim3(NROW/32, 4), 128, 0, stream>>>(oe_bf, wsqT, ws_qb, nullptr,
                                                      kvbs, 128, 256, 2, 0);
    kvtrans_kernel<<<dim3(L_/32, B_*NH_), 256, 0, stream>>>(kvbs, kvT);
    // 6: self attention (flash v13: 256 thr, 2 blocks/CU, no prefetch)
    flash_attn_kernel<<<dim3(B_*NH_, L_/32), 256, 0, stream>>>(kvbs, kvbs, kvT,
                                                               nullptr, mobs, abuf);
    // 7: x = relu(oe + attn @ ws_o + ws_ob)
    gemm_kernel<<<dim3(NROW/32, 2), 128, 0, stream>>>(abuf, wsoT, ws_ob, oe_bf,
                                                      x_bf, 256, 128, 1, 1);
    // 8-13: mixing-weights path
    gemm_kernel<<<dim3(NROW/32, 4), 128, 0, stream>>>(x_bf, wwqT, ww_qb, nullptr,
                                                      kvmw, 128, 256, 2, 0);
    mwpartial_kernel<<<dim3(32, NH_, B_), 256, 0, stream>>>(qmwb, kvmw, mobs,
                                                            mwO, mwM, mwL);
    mwproj2_kernel<<<dim3(B_, G_), 256, 0, stream>>>(mwO, mwM, mwL, mix_wt,
                                                     ww_o, ww_ob, mwq);
    mwfinal_kernel<<<B_, 64, 0, stream>>>(mwq, w_mix, b_mix,
                                          out + (size_t)B_ * G_ * L_ * H_);
    // 14: merged cross projections: [qe_bf; x_bf](16384x128) @ wc_q -> [qcb; kvcb]
    gemm_kernel<<<dim3(2*NROW/32, 4), 128, 0, stream>>>(qe_bf, wcqT, wc_qb, nullptr,
                                                        qcb, 128, 256, 2, 0);
    kvtrans_kernel<<<dim3(L_/32, B_*NH_), 256, 0, stream>>>(kvcb, kvT);
    // 16: cross attention
    flash_attn_kernel<<<dim3(B_*NH_, L_/32), 256, 0, stream>>>(qcb, kvcb, kvT,
                                                               mq, mobs, abuf2);
    // 17: x2 = relu(qe + attn2 @ wc_o + wc_ob)
    gemm_kernel<<<dim3(NROW/32, 2), 128, 0, stream>>>(abuf2, wcoT, wc_ob, qe_bf,
                                                      x2_bf, 256, 128, 1, 1);
    // 18: split + transpose store (MFMA)
    gemm_kernel<<<dim3(NROW/32, 20), 128, 0, stream>>>(x2_bf, wsplT, b_split, nullptr,
                                                       out, 128, 1280, 3, 0);

    (void)in_sizes; (void)n_in; (void)out_size;
}

// Round 15
// 423.193 us; speedup vs baseline: 1.2672x; 1.0164x over previous
//
#include <hip/hip_runtime.h>
#include <hip/hip_bf16.h>

#define B_  4
#define L_  2048      // LO == LQ == 2048
#define H_  128
#define NH_ 2
#define G_  10
#define NIN_ 41

typedef __hip_bfloat16 bf16;
typedef __attribute__((ext_vector_type(8))) short bf16x8s;  // 8 bf16 = 4 VGPRs
typedef __attribute__((ext_vector_type(4))) float f32x4;

__device__ __forceinline__ unsigned short f2bf_bits(float x) {
    __hip_bfloat16 h = __float2bfloat16(x);
    return *reinterpret_cast<unsigned short*>(&h);
}
__device__ __forceinline__ float us2f(unsigned short s) {
    return __uint_as_float(((unsigned int)s) << 16);
}

// ---------------------------------------------------------------------------
// K1+K2 merged: featurize query rows (blk < NROW) and obs rows (blk >= NROW)
// ---------------------------------------------------------------------------
__global__ __launch_bounds__(128)
void featall_kernel(const float* __restrict__ xq, const float* __restrict__ mq,
                    const float* __restrict__ obs, const float* __restrict__ mobs,
                    const float* __restrict__ w_q0, const float* __restrict__ b_q0,
                    const float* __restrict__ w_q1, const float* __restrict__ b_q1,
                    const float* __restrict__ w_cq, const float* __restrict__ b_cq,
                    const float* __restrict__ w_o0, const float* __restrict__ b_o0,
                    const float* __restrict__ w_o1, const float* __restrict__ b_o1,
                    const float* __restrict__ w_cobs, const float* __restrict__ b_cobs,
                    bf16* __restrict__ featq, bf16* __restrict__ feato)
{
    const int blk = blockIdx.x;
    const int j   = threadIdx.x;
    const int NROW = B_ * L_;
    if (blk < NROW) {
        const int row = blk;
        const float t   = xq[row * 2 + 0];
        const float chf = xq[row * 2 + 1];
        int ch = (int)chf; ch = max(0, min(NIN_ - 1, ch));
        const float m   = mq[row];
        float tf;
        if (j == 0) tf = t * w_q0[0] + b_q0[0];
        else        tf = __sinf(t * w_q1[j - 1] + b_q1[j - 1]);
        float cf = fmaxf(w_cq[ch * H_ + j] + b_cq[j], 0.f);
        featq[(size_t)row * 256 + j]       = __float2bfloat16(tf * m);
        featq[(size_t)row * 256 + 128 + j] = __float2bfloat16(cf * m);
    } else {
        const int row = blk - NROW;
        const float t   = obs[row * 3 + 0];
        const float chf = obs[row * 3 + 1];
        const float xv  = obs[row * 3 + 2];
        int ch = (int)chf; ch = max(0, min(NIN_ - 1, ch));
        const float m   = mobs[row];
        float tf;
        if (j == 0) tf = t * w_o0[0] + b_o0[0];
        else        tf = __sinf(t * w_o1[j - 1] + b_o1[j - 1]);
        float cf = fmaxf(w_cobs[ch * H_ + j] + b_cobs[j], 0.f);
        bf16* r = feato + (size_t)row * 288;
        r[j]       = __float2bfloat16(tf * m);
        r[128 + j] = __float2bfloat16(cf * m);
        if (j == 0) r[256] = __float2bfloat16(xv * m);
        if (j < 31) r[257 + j] = __float2bfloat16(0.f);
    }
}

// ---------------------------------------------------------------------------
// All weight transposes (fp32 K x N -> bf16 N x Kp, zero pad k>=K) in 1 launch
// ---------------------------------------------------------------------------
struct WtArgs {
    const float* W[8];
    bf16* T[8];
    int K[8], Kp[8], N[8];
};
__global__ __launch_bounds__(288)
void wtrans_all_kernel(WtArgs a)
{
    const int i = blockIdx.y, n = blockIdx.x, k = threadIdx.x;
    if (n >= a.N[i] || k >= a.Kp[i]) return;
    a.T[i][(size_t)n * a.Kp[i] + k] =
        (k < a.K[i]) ? __float2bfloat16(a.W[i][(size_t)k * a.N[i] + n])
                     : __float2bfloat16(0.f);
}

// ---------------------------------------------------------------------------
// KV transpose v2: in (BH, L, H) -> out (BH, H, L). 32-row tiles,
// grid (L/32, BH) = 512 blocks, 256 thr.
// ---------------------------------------------------------------------------
__global__ __launch_bounds__(256)
void kvtrans_kernel(const bf16* __restrict__ in, bf16* __restrict__ out)
{
    __shared__ unsigned short tile[32 * 136];
    const int tid = threadIdx.x;
    const int l0 = blockIdx.x * 32;
    const int bh = blockIdx.y;
    const unsigned short* src = (const unsigned short*)(in + (size_t)bh * L_ * H_);
    unsigned short* dst = (unsigned short*)(out + (size_t)bh * H_ * L_);
    #pragma unroll
    for (int p = 0; p < 2; p++) {
        const int l = p * 16 + (tid >> 4);
        const int d0 = (tid & 15) * 8;
        *(uint4*)&tile[l * 136 + d0] = *(const uint4*)&src[(size_t)(l0 + l) * H_ + d0];
    }
    __syncthreads();
    const int d  = tid >> 1;
    const int lh = (tid & 1) * 16;
    unsigned short buf[16];
    #pragma unroll
    for (int j = 0; j < 16; j++) buf[j] = tile[(lh + j) * 136 + d];
    #pragma unroll
    for (int j = 0; j < 2; j++)
        *(uint4*)&dst[(size_t)d * L_ + l0 + lh + j * 8] = *(uint4*)&buf[j * 8];
}

// ---------------------------------------------------------------------------
// GEMM v3 (LDS stage-once, half-height tiles for occupancy):
// C = A(bf16 M x K) @ WT(bf16 N x K) + bias(fp32), optional bf16 residual R.
// Block = 128 thr = 2 waves, tile 32x64. ONE barrier, barrier-free MFMA loop.
// Grid (M/32, N/64). K multiple of 32, K <= 288.
// ---------------------------------------------------------------------------
__global__ __launch_bounds__(128)
void gemm_kernel(const bf16* __restrict__ A, const bf16* __restrict__ WT,
                 const float* __restrict__ bias, const bf16* __restrict__ R,
                 void* __restrict__ out, int K, int N, int mode, int do_relu)
{
    __shared__ __align__(16) unsigned short As[32 * 296];   // 18944 B max
    __shared__ __align__(16) unsigned short Ws[64 * 296];   // 37888 B max

    const int tid  = threadIdx.x;
    const int wave = tid >> 6, lane = tid & 63;
    const int quad = lane >> 4, l15 = lane & 15;
    const int m0 = blockIdx.x * 32;
    const int n0 = blockIdx.y * 64;
    const int Kp = K + 8;

    const int srow = tid >> 2;           // 0..31
    const int sc0  = (tid & 3) * 8;
    {
        const bf16* arow = A  + (size_t)(m0 + srow) * K;
        const bf16* w0   = WT + (size_t)(n0 + srow) * K;
        const bf16* w1   = WT + (size_t)(n0 + 32 + srow) * K;
        for (int col = sc0; col < K; col += 32) {
            *(uint4*)&As[srow * Kp + col]        = *(const uint4*)(arow + col);
            *(uint4*)&Ws[srow * Kp + col]        = *(const uint4*)(w0 + col);
            *(uint4*)&Ws[(32 + srow) * Kp + col] = *(const uint4*)(w1 + col);
        }
    }
    __syncthreads();

    f32x4 acc[4];
    #pragma unroll
    for (int c = 0; c < 4; c++) acc[c] = (f32x4){0.f, 0.f, 0.f, 0.f};

    const unsigned short* am = &As[(wave * 16 + l15) * Kp + quad * 8];
    #pragma unroll 4
    for (int kc = 0; kc < K; kc += 32) {
        bf16x8s af = *(const bf16x8s*)(am + kc);
        #pragma unroll
        for (int c = 0; c < 4; c++) {
            bf16x8s wf = *(const bf16x8s*)&Ws[(c * 16 + l15) * Kp + kc + quad * 8];
            acc[c] = __builtin_amdgcn_mfma_f32_16x16x32_bf16(af, wf, acc[c], 0, 0, 0);
        }
    }

    const int mw0 = m0 + wave * 16;
    #pragma unroll
    for (int c = 0; c < 4; c++) {
        const int n = n0 + c * 16 + l15;
        const float bv = bias[n];
        #pragma unroll
        for (int r = 0; r < 4; r++) {
            const int m = mw0 + quad * 4 + r;
            float v = acc[c][r] + bv;
            if (R != nullptr) v += __bfloat162float(R[(size_t)m * N + n]);
            if (do_relu) v = fmaxf(v, 0.f);
            if (mode == 0) {
                ((float*)out)[(size_t)m * N + n] = v;
            } else if (mode == 1) {
                ((bf16*)out)[(size_t)m * N + n] = __float2bfloat16(v);
            } else if (mode == 2) {
                const int b = m >> 11, l = m & 2047, hh = n >> 7, d = n & 127;
                ((bf16*)out)[(((size_t)(b * NH_ + hh)) * L_ + l) * H_ + d] = __float2bfloat16(v);
            } else {
                const int b = m >> 11, q = m & 2047, g = n >> 7, hh = n & 127;
                ((float*)out)[(((size_t)(b * G_ + g)) * L_ + q) * H_ + hh] = v;
            }
        }
    }
}

// ---------------------------------------------------------------------------
// Flash attention v14: r14 chassis (256 thr, 2 blocks/CU, no cross-barrier
// prefetch — 66.7us clean) + split staging: after bar1 (everyone done
// reading Ks), issue K-next global loads, run softmax while they fly,
// commit K-next to LDS, then PV; V-next staged in its own window.
// All staging state lives WITHIN one barrier window (no regs across
// barriers = no r8 scratch pathology). 3 barriers/iter; the co-resident
// block covers barrier stalls.
// Canary: WRITE_SIZE >> 4 MB = compiler scratch pathology -> revert to r14.
// ---------------------------------------------------------------------------
#define KT_S 136    // K tile row stride (shorts): 272 B, 16B-aligned
#define VT_S 72     // V^T tile row stride (shorts): 144 B, 16B-aligned
#define PS_S 72     // P row stride (shorts)

__global__ __launch_bounds__(256, 2)
void flash_attn_kernel(const bf16* __restrict__ Qb, const bf16* __restrict__ KVb,
                       const bf16* __restrict__ KVTb,
                       const float* __restrict__ mQ, const float* __restrict__ mK,
                       bf16* __restrict__ O)
{
    // Ks [2][64][136] = 34816 B | Vs [2][128][72] = 36864 B
    // Ps [4][16][72]  =  9216 B  -> 80896 B total (2 blocks/CU)
    // Combine (aliased post-barrier): Ocomb 32*132*4 = 16896 B,
    //   mcomb @16896 (128 B), lcomb @17024 (128 B)
    __shared__ __align__(16) char smem[80896];
    unsigned short* Ks = (unsigned short*)smem;
    unsigned short* Vs = (unsigned short*)(smem + 34816);
    unsigned short* Ps = (unsigned short*)(smem + 71680);
    float* Ocomb = (float*)smem;
    float* mcomb = (float*)(smem + 16896);
    float* lcomb = (float*)(smem + 17024);

    const int tid  = threadIdx.x;
    const int lane = tid & 63;
    const int wave = tid >> 6;         // 0..3
    const int half = wave >> 1;        // K-split half
    const int wq   = wave & 1;         // q sub-tile within block (16 rows)
    const int quad = lane >> 4;
    const int l15  = lane & 15;
    const int t128 = tid & 127;        // staging id within half
    const int bh = blockIdx.x, b = bh >> 1, h = bh & 1;
    const int q0 = blockIdx.y * 32;

    const bf16* kvb = KVb  + (size_t)bh * L_ * H_;
    const bf16* kvt = KVTb + (size_t)bh * H_ * L_;
    const float* mkb = mK + b * L_;

    // ---- Q fragments (16 q-rows per wave, from global, once) ----
    const bf16* qrow = Qb + ((size_t)bh * L_ + q0 + wq * 16 + l15) * H_;
    bf16x8s qf[4];
    #pragma unroll
    for (int kc = 0; kc < 4; kc++)
        qf[kc] = *(const bf16x8s*)(qrow + kc * 32 + quad * 8);

    bool qz[4];
    #pragma unroll
    for (int r = 0; r < 4; r++)
        qz[r] = (mQ != nullptr) && (mQ[b * L_ + q0 + wq * 16 + quad * 4 + r] == 0.f);

    float mo[4], li[4];
    f32x4 Oacc[8];
    #pragma unroll
    for (int r = 0; r < 4; r++) { mo[r] = -1e30f; li[r] = 0.f; }
    #pragma unroll
    for (int c = 0; c < 8; c++) Oacc[c] = (f32x4){0.f, 0.f, 0.f, 0.f};

    const float SCALE = 0.08838834764831845f;    // 1/sqrt(128)
    unsigned short* KsH = Ks + half * 64 * KT_S;
    unsigned short* VsH = Vs + half * 128 * VT_S;
    unsigned short* pw  = Ps + wave * 16 * PS_S;

    // staging geometry (within the 128-thread half):
    // K: rows krow_b + 8p (p<8), 16 thr/row; V: rows vrow_b + 16p, 8 thr/row
    const int krow_b = t128 >> 4, kcol = (t128 & 15) * 8;
    const int vrow_b = t128 >> 3, vcol = (t128 & 7) * 8;

    const int ks0 = half * 1024;

    // ---- stage tile 0 (load->store, nothing held afterwards) ----
    {
        const int kb = ks0;
        uint4 t0[8];
        #pragma unroll
        for (int p = 0; p < 8; p++)
            t0[p] = *(const uint4*)(kvb + (size_t)(kb + p * 8 + krow_b) * H_ + kcol);
        #pragma unroll
        for (int p = 0; p < 8; p++)
            *(uint4*)&KsH[(p * 8 + krow_b) * KT_S + kcol] = t0[p];
        #pragma unroll
        for (int p = 0; p < 8; p++)
            t0[p] = *(const uint4*)(kvt + (size_t)(p * 16 + vrow_b) * L_ + kb + vcol);
        #pragma unroll
        for (int p = 0; p < 8; p++)
            *(uint4*)&VsH[(p * 16 + vrow_b) * VT_S + vcol] = t0[p];
    }
    __syncthreads();

    for (int it = 0; it < 16; it++) {
        const int kb = ks0 + it * 64;
        const bool more = (it + 1 < 16);

        // ---- k-mask as additive offset ----
        float koff[4];
        #pragma unroll
        for (int t = 0; t < 4; t++)
            koff[t] = (mkb[kb + t * 16 + l15] != 0.f) ? 0.f : -1000000.f;

        // ---- S = Q K^T over 4 16-key sub-tiles (K-frags from LDS) ----
        f32x4 sa[4];
        #pragma unroll
        for (int t = 0; t < 4; t++) sa[t] = (f32x4){0.f, 0.f, 0.f, 0.f};
        #pragma unroll
        for (int t = 0; t < 4; t++)
            #pragma unroll
            for (int kc = 0; kc < 4; kc++) {
                bf16x8s kf = *(const bf16x8s*)&KsH[(t * 16 + l15) * KT_S + kc * 32 + quad * 8];
                sa[t] = __builtin_amdgcn_mfma_f32_16x16x32_bf16(qf[kc], kf, sa[t], 0, 0, 0);
            }

        // ---- bar1: all waves done reading Ks for this iter ----
        __syncthreads();

        // ---- issue K-next global loads (latency hidden under softmax) ----
        uint4 tk[8];
        if (more) {
            const int kn = kb + 64;
            #pragma unroll
            for (int p = 0; p < 8; p++)
                tk[p] = *(const uint4*)(kvb + (size_t)(kn + p * 8 + krow_b) * H_ + kcol);
        }

        // ---- mask + online softmax over 64 keys (K loads in flight) ----
        float s[4][4], mx[4];
        #pragma unroll
        for (int r = 0; r < 4; r++) {
            #pragma unroll
            for (int t = 0; t < 4; t++) {
                const float v = sa[t][r] * SCALE + koff[t];
                s[t][r] = qz[r] ? -1000000.f : v;   // exact -1e6 for masked queries
            }
            mx[r] = fmaxf(fmaxf(s[0][r], s[1][r]), fmaxf(s[2][r], s[3][r]));
        }
        #pragma unroll
        for (int off = 1; off < 16; off <<= 1)
            #pragma unroll
            for (int r = 0; r < 4; r++) mx[r] = fmaxf(mx[r], __shfl_xor(mx[r], off));

        float al[4], rs[4];
        #pragma unroll
        for (int r = 0; r < 4; r++) {
            const float mn = fmaxf(mo[r], mx[r]);
            al[r] = __expf(mo[r] - mn);
            mo[r] = mn;
            rs[r] = 0.f;
        }
        #pragma unroll
        for (int t = 0; t < 4; t++)
            #pragma unroll
            for (int r = 0; r < 4; r++) {
                const float p = __expf(s[t][r] - mo[r]);
                rs[r] += p;
                pw[(quad * 4 + r) * PS_S + t * 16 + l15] = f2bf_bits(p);
            }
        #pragma unroll
        for (int off = 1; off < 16; off <<= 1)
            #pragma unroll
            for (int r = 0; r < 4; r++) rs[r] += __shfl_xor(rs[r], off);
        #pragma unroll
        for (int r = 0; r < 4; r++) li[r] = li[r] * al[r] + rs[r];
        #pragma unroll
        for (int c = 0; c < 8; c++)
            #pragma unroll
            for (int r = 0; r < 4; r++) Oacc[c][r] *= al[r];

        // ---- commit K-next to LDS (within this barrier window) ----
        if (more) {
            #pragma unroll
            for (int p = 0; p < 8; p++)
                *(uint4*)&KsH[(p * 8 + krow_b) * KT_S + kcol] = tk[p];
        }

        // ---- P A-frags (wave-private LDS round trip) ----
        bf16x8s pf0 = *(bf16x8s*)&pw[l15 * PS_S + quad * 8];
        bf16x8s pf1 = *(bf16x8s*)&pw[l15 * PS_S + 32 + quad * 8];

        // ---- O += P V (V^T frags from LDS) ----
        #pragma unroll
        for (int c = 0; c < 8; c++) {
            bf16x8s v0 = *(const bf16x8s*)&VsH[(c * 16 + l15) * VT_S + quad * 8];
            bf16x8s v1 = *(const bf16x8s*)&VsH[(c * 16 + l15) * VT_S + 32 + quad * 8];
            Oacc[c] = __builtin_amdgcn_mfma_f32_16x16x32_bf16(pf0, v0, Oacc[c], 0, 0, 0);
            Oacc[c] = __builtin_amdgcn_mfma_f32_16x16x32_bf16(pf1, v1, Oacc[c], 0, 0, 0);
        }

        // ---- bar2: Vs reads done everywhere; Ks writes visible ----
        __syncthreads();
        if (more) {
            const int kn = kb + 64;
            uint4 tv[8];
            #pragma unroll
            for (int p = 0; p < 8; p++)
                tv[p] = *(const uint4*)(kvt + (size_t)(p * 16 + vrow_b) * L_ + kn + vcol);
            #pragma unroll
            for (int p = 0; p < 8; p++)
                *(uint4*)&VsH[(p * 16 + vrow_b) * VT_S + vcol] = tv[p];
            __syncthreads();           // bar3: Vs-next visible for next iter
        }
    }

    // ---- 2-way K-split combine (Ocomb aliases the tiles, post-barrier) ----
    if (half == 1) {
        #pragma unroll
        for (int c = 0; c < 8; c++)
            #pragma unroll
            for (int r = 0; r < 4; r++)
                Ocomb[(size_t)(wq * 16 + quad * 4 + r) * 132 + c * 16 + l15] = Oacc[c][r];
        if (l15 == 0) {
            #pragma unroll
            for (int r = 0; r < 4; r++) {
                mcomb[wq * 16 + quad * 4 + r] = mo[r];
                lcomb[wq * 16 + quad * 4 + r] = li[r];
            }
        }
    }
    __syncthreads();
    if (half == 0) {
        bf16* orow = O + ((size_t)b * L_ + q0 + wq * 16) * (NH_ * H_) + h * H_;
        #pragma unroll
        for (int r = 0; r < 4; r++) {
            const int row = quad * 4 + r;
            const float m1 = mcomb[wq * 16 + row];
            const float l1 = lcomb[wq * 16 + row];
            const float M  = fmaxf(mo[r], m1);
            const float a0 = __expf(mo[r] - M);
            const float a1 = __expf(m1 - M);
            const float inv = 1.f / (a0 * li[r] + a1 * l1);
            #pragma unroll
            for (int c = 0; c < 8; c++)
                orow[(size_t)row * (NH_ * H_) + c * 16 + l15] =
                    __float2bfloat16((a0 * Oacc[c][r] +
                                      a1 * Ocomb[(size_t)(wq * 16 + row) * 132 + c * 16 + l15]) * inv);
        }
    }
}

// ---------------------------------------------------------------------------
// qmw builder: mix_wt(10x128) @ ww_q(128x256) + b -> bf16 per-head (2,16,128)
// ---------------------------------------------------------------------------
__global__ __launch_bounds__(256)
void qmwb_kernel(const float* __restrict__ mixwt, const float* __restrict__ W,
                 const float* __restrict__ bias, bf16* __restrict__ qmwb)
{
    const int g = blockIdx.x;          // 0..15
    const int c = threadIdx.x;         // 0..255
    const int h = c >> 7, d = c & 127;
    if (g >= G_) { qmwb[((size_t)h * 16 + g) * 128 + d] = __float2bfloat16(0.f); return; }
    __shared__ float xr[128];
    if (c < 128) xr[c] = mixwt[g * 128 + c];
    __syncthreads();
    float acc = bias[c];
    #pragma unroll 8
    for (int i = 0; i < 128; i++)
        acc += xr[i] * W[i * 256 + c];
    qmwb[((size_t)h * 16 + g) * 128 + d] = __float2bfloat16(acc);
}

// ---------------------------------------------------------------------------
// mw partial attention v2: 32-way K-split (64-key tiles).
// grid (32, NH, B) = 256 blocks, 256 threads.
// ---------------------------------------------------------------------------
__global__ __launch_bounds__(256)
void mwpartial_kernel(const bf16* __restrict__ qmwb, const bf16* __restrict__ kvmw,
                      const float* __restrict__ mK,
                      float* __restrict__ mwO, float* __restrict__ mwM,
                      float* __restrict__ mwL)
{
    __shared__ __align__(16) unsigned short Ks[64 * 136];
    __shared__ float Qs[10 * 128];
    __shared__ float sc[10 * 64];
    __shared__ float mst[10], lst[10];

    const int tid = threadIdx.x;
    const int split = blockIdx.x, h = blockIdx.y, b = blockIdx.z;
    const int kbase = split * 64;
    const float SCALE = 0.08838834764831845f;

    for (int idx = tid; idx < 1280; idx += 256)
        Qs[idx] = __bfloat162float(qmwb[((size_t)h * 16 + (idx >> 7)) * 128 + (idx & 127)]);
    {
        const int rr = tid >> 2, qt = tid & 3;   // 64 rows, 4 thr/row
        const bf16* src = kvmw + (((size_t)(b * NH_ + h)) * L_ + kbase + rr) * H_ + qt * 32;
        #pragma unroll
        for (int i = 0; i < 4; i++)
            *(uint4*)(&Ks[rr * 136 + qt * 32 + i * 8]) = *(const uint4*)(src + i * 8);
    }
    __syncthreads();

    {
        const int j = tid & 63, qg = tid >> 6;   // key j, query-group qg 0..3
        float acc[3] = {0.f, 0.f, 0.f};
        for (int dc = 0; dc < 128; dc += 8) {
            bf16x8s kv = *(bf16x8s*)(&Ks[j * 136 + dc]);
            float kf[8];
            #pragma unroll
            for (int e = 0; e < 8; e++) kf[e] = us2f(((unsigned short*)&kv)[e]);
            #pragma unroll
            for (int qq = 0; qq < 3; qq++) {
                const int q = qg + 4 * qq;       // {qg, qg+4, qg+8}
                if (q < G_) {
                    const float* Qrow = &Qs[q * 128 + dc];
                    #pragma unroll
                    for (int e = 0; e < 8; e++) acc[qq] += Qrow[e] * kf[e];
                }
            }
        }
        const bool kz = (mK[b * L_ + kbase + j] == 0.f);
        #pragma unroll
        for (int qq = 0; qq < 3; qq++) {
            const int q = qg + 4 * qq;
            if (q < G_) sc[q * 64 + j] = kz ? -1000000.f : acc[qq] * SCALE;
        }
    }
    __syncthreads();
    if (tid < 160) {
        const int q = tid >> 4, t16 = tid & 15;
        float m = -3.4e38f;
        for (int jj = t16; jj < 64; jj += 16) m = fmaxf(m, sc[q * 64 + jj]);
        #pragma unroll
        for (int off = 1; off < 16; off <<= 1) m = fmaxf(m, __shfl_xor(m, off));
        if (t16 == 0) mst[q] = m;
    }
    __syncthreads();
    for (int idx = tid; idx < 640; idx += 256)
        sc[idx] = __expf(sc[idx] - mst[idx >> 6]);
    __syncthreads();
    if (tid < 160) {
        const int q = tid >> 4, t16 = tid & 15;
        float s = 0.f;
        for (int jj = t16; jj < 64; jj += 16) s += sc[q * 64 + jj];
        #pragma unroll
        for (int off = 1; off < 16; off <<= 1) s += __shfl_xor(s, off);
        if (t16 == 0) lst[q] = s;
    }
    __syncthreads();
    {
        const int d = tid & 127, qh = tid >> 7;  // 0..1, 5 queries each
        float acc[5] = {0.f, 0.f, 0.f, 0.f, 0.f};
        for (int jj = 0; jj < 64; jj++) {
            const float v = us2f(Ks[jj * 136 + d]);
            #pragma unroll
            for (int qq = 0; qq < 5; qq++)
                acc[qq] += sc[(qh * 5 + qq) * 64 + jj] * v;
        }
        const size_t base = ((size_t)(b * NH_ + h) * 32 + split) * 10;
        #pragma unroll
        for (int qq = 0; qq < 5; qq++)
            mwO[(base + qh * 5 + qq) * 128 + d] = acc[qq];
    }
    if (tid < 10) {
        const size_t base = ((size_t)(b * NH_ + h) * 32 + split) * 10;
        mwM[base + tid] = mst[tid];
        mwL[base + tid] = lst[tid];
    }
}

// ---------------------------------------------------------------------------
// mw proj v2 (parallelized tail part 1): grid (B, G) = 40 blocks, 256 thr.
// ---------------------------------------------------------------------------
__global__ __launch_bounds__(256)
void mwproj2_kernel(const float* __restrict__ mwO, const float* __restrict__ mwM,
                    const float* __restrict__ mwL, const float* __restrict__ mixwt,
                    const float* __restrict__ W, const float* __restrict__ bias,
                    float* __restrict__ mwq)
{
    __shared__ float mwat[256];
    __shared__ float part[256];

    const int b = blockIdx.x, q = blockIdx.y;
    const int tid = threadIdx.x;
    const int h = tid >> 7, d = tid & 127;

    // combine: thread tid owns column h*128+d
    const size_t hb = (size_t)(b * NH_ + h) * 32;
    float M = -3.4e38f;
    for (int s = 0; s < 32; s++) M = fmaxf(M, mwM[(hb + s) * 10 + q]);
    float l = 0.f, o = 0.f;
    for (int s = 0; s < 32; s++) {
        const float a = __expf(mwM[(hb + s) * 10 + q] - M);
        l += a * mwL[(hb + s) * 10 + q];
        o += a * mwO[((hb + s) * 10 + q) * 128 + d];
    }
    mwat[tid] = o / l;
    __syncthreads();

    // proj: output dim d2; 2 threads per output, each half of the 256-dot
    const int d2 = tid & 127, hf = tid >> 7;
    float acc = 0.f;
    #pragma unroll 8
    for (int i = hf * 128; i < hf * 128 + 128; i++)
        acc += mwat[i] * W[i * 128 + d2];
    part[tid] = acc;
    __syncthreads();
    if (tid < 128)
        mwq[((size_t)b * G_ + q) * 128 + tid] =
            mixwt[q * 128 + tid] + bias[tid] + part[tid] + part[128 + tid];
}

// mw final: z[q] = dot(mwq[b][q], wmix) + b ; softmax over q. grid B_, 64 thr.
__global__ __launch_bounds__(64)
void mwfinal_kernel(const float* __restrict__ MW, const float* __restrict__ wmix,
                    const float* __restrict__ bmix, float* __restrict__ out)
{
    const int b = blockIdx.x;
    const int g = threadIdx.x;
    __shared__ float z[16];
    if (g < G_) {
        float acc = bmix[0];
        for (int i = 0; i < 128; i++)
            acc += MW[((size_t)b * G_ + g) * 128 + i] * wmix[i];
        z[g] = acc;
    }
    __syncthreads();
    if (g == 0) {
        float mx = -3.4e38f;
        for (int i = 0; i < G_; i++) mx = fmaxf(mx, z[i]);
        float e[G_]; float s = 0.f;
        for (int i = 0; i < G_; i++) { e[i] = __expf(z[i] - mx); s += e[i]; }
        for (int i = 0; i < G_; i++) out[b * G_ + i] = e[i] / s;
    }
}

// ---------------------------------------------------------------------------
extern "C" void kernel_launch(void* const* d_in, const int* in_sizes, int n_in,
                              void* d_out, int out_size, void* d_ws, size_t ws_size,
                              hipStream_t stream)
{
    const float* obs    = (const float*)d_in[0];
    const float* mobs   = (const float*)d_in[1];
    const float* xq     = (const float*)d_in[2];
    const float* mq     = (const float*)d_in[3];
    const float* w_q0   = (const float*)d_in[4];
    const float* b_q0   = (const float*)d_in[5];
    const float* w_q1   = (const float*)d_in[6];
    const float* b_q1   = (const float*)d_in[7];
    const float* w_o0   = (const float*)d_in[8];
    const float* b_o0   = (const float*)d_in[9];
    const float* w_o1   = (const float*)d_in[10];
    const float* b_o1   = (const float*)d_in[11];
    const float* w_cobs = (const float*)d_in[12];
    const float* b_cobs = (const float*)d_in[13];
    const float* w_cq   = (const float*)d_in[14];
    const float* b_cq   = (const float*)d_in[15];
    const float* w_qp   = (const float*)d_in[16];
    const float* b_qp   = (const float*)d_in[17];
    const float* w_kp   = (const float*)d_in[18];
    const float* b_kp   = (const float*)d_in[19];
    const float* ws_q   = (const float*)d_in[20];
    const float* ws_qb  = (const float*)d_in[21];
    const float* ws_o   = (const float*)d_in[22];
    const float* ws_ob  = (const float*)d_in[23];
    const float* ww_q   = (const float*)d_in[24];
    const float* ww_qb  = (const float*)d_in[25];
    const float* ww_o   = (const float*)d_in[26];
    const float* ww_ob  = (const float*)d_in[27];
    const float* wc_q   = (const float*)d_in[28];
    const float* wc_qb  = (const float*)d_in[29];
    const float* wc_o   = (const float*)d_in[30];
    const float* wc_ob  = (const float*)d_in[31];
    const float* w_split= (const float*)d_in[32];
    const float* b_split= (const float*)d_in[33];
    const float* mix_wt = (const float*)d_in[34];
    const float* w_mix  = (const float*)d_in[35];
    const float* b_mix  = (const float*)d_in[36];

    float* out = (float*)d_out;
    char* ws  = (char*)d_ws;

    const size_t MB = (size_t)1 << 20;
    const size_t KB = (size_t)1 << 10;
    if (ws_size < 31 * MB) return;

    const int NROW = B_ * L_;          // 8192
    // layout (<=31 MB). qcb+kvcb and qe_bf+x_bf pairs MUST be contiguous.
    bf16* featq = (bf16*)(ws + 0);                 // 4 MB  -> kvbs, later qcb
    bf16* feato = (bf16*)(ws + 4 * MB);            // 4.5 MB -> later kvcb (at +4MB!)
    bf16* qe_bf = (bf16*)(ws + 8 * MB + 512 * KB); // 2 MB  \ contiguous pair
    bf16* x_bf  = (bf16*)(ws + 10 * MB + 512 * KB);// 2 MB  / for merged gemm
    bf16* oe_bf = (bf16*)(ws + 12 * MB + 512 * KB);// 2 MB
    bf16* abuf  = (bf16*)(ws + 14 * MB + 512 * KB);// 4 MB -> abuf2
    bf16* x2_bf = (bf16*)(ws + 18 * MB + 512 * KB);// 2 MB
    bf16* kvmw  = (bf16*)(ws + 20 * MB + 512 * KB);// 4 MB
    bf16* kvT   = (bf16*)(ws + 24 * MB + 512 * KB);// 4 MB (BH,H,L), self then cross
    char* wbase = ws + 28 * MB + 512 * KB;         // ~2.5 MB of weights/smalls
    bf16* wqpT  = (bf16*)(wbase + 0);              // 64 KB (128 x 256)
    bf16* wkpT  = (bf16*)(wbase + 64 * KB);        // 72 KB (128 x 288)
    bf16* wsqT  = (bf16*)(wbase + 136 * KB);       // 64 KB (256 x 128)
    bf16* wsoT  = (bf16*)(wbase + 200 * KB);       // 64 KB (128 x 256)
    bf16* wwqT  = (bf16*)(wbase + 264 * KB);       // 64 KB
    bf16* wcqT  = (bf16*)(wbase + 328 * KB);       // 64 KB
    bf16* wcoT  = (bf16*)(wbase + 392 * KB);       // 64 KB
    bf16* wsplT = (bf16*)(wbase + 456 * KB);       // 320 KB (1280 x 128)
    bf16* qmwb  = (bf16*)(wbase + 776 * KB);       // 8 KB (2,16,128)
    float* mwO  = (float*)(wbase + 784 * KB);      // 1280 KB (B,NH,32,10,128) fp32
    float* mwM  = (float*)(wbase + 2064 * KB);     // 10 KB
    float* mwL  = (float*)(wbase + 2080 * KB);     // 10 KB
    float* mwq  = (float*)(wbase + 2096 * KB);     // 20 KB (B,G,128) fp32
    bf16* kvbs  = featq;                           // self QKV (B,NH,L,H)
    bf16* qcb   = featq;                           // cross Q  (B,NH,L,H)
    bf16* kvcb  = (bf16*)(ws + 4 * MB);            // cross KV = qcb + 4MB
    bf16* abuf2 = abuf;

    // 0: all weight transposes in one launch
    WtArgs wa;
    wa.W[0]=w_qp;   wa.T[0]=wqpT;  wa.K[0]=256; wa.Kp[0]=256; wa.N[0]=128;
    wa.W[1]=w_kp;   wa.T[1]=wkpT;  wa.K[1]=257; wa.Kp[1]=288; wa.N[1]=128;
    wa.W[2]=ws_q;   wa.T[2]=wsqT;  wa.K[2]=128; wa.Kp[2]=128; wa.N[2]=256;
    wa.W[3]=ws_o;   wa.T[3]=wsoT;  wa.K[3]=256; wa.Kp[3]=256; wa.N[3]=128;
    wa.W[4]=ww_q;   wa.T[4]=wwqT;  wa.K[4]=128; wa.Kp[4]=128; wa.N[4]=256;
    wa.W[5]=wc_q;   wa.T[5]=wcqT;  wa.K[5]=128; wa.Kp[5]=128; wa.N[5]=256;
    wa.W[6]=wc_o;   wa.T[6]=wcoT;  wa.K[6]=256; wa.Kp[6]=256; wa.N[6]=128;
    wa.W[7]=w_split;wa.T[7]=wsplT; wa.K[7]=128; wa.Kp[7]=128; wa.N[7]=1280;
    wtrans_all_kernel<<<dim3(1280, 8), 288, 0, stream>>>(wa);

    // qmw query builder (depends only on inputs; fills pipeline gap early)
    qmwb_kernel<<<16, 256, 0, stream>>>(mix_wt, ww_q, ww_qb, qmwb);

    // 1-2: featurize (merged)
    featall_kernel<<<2 * NROW, 128, 0, stream>>>(xq, mq, obs, mobs,
                                                 w_q0, b_q0, w_q1, b_q1, w_cq, b_cq,
                                                 w_o0, b_o0, w_o1, b_o1, w_cobs, b_cobs,
                                                 featq, feato);
    // 3-4: embed projections (MFMA, 32x64-tile LDS gemm)
    gemm_kernel<<<dim3(NROW/32, 2), 128, 0, stream>>>(featq, wqpT, b_qp, nullptr,
                                                      qe_bf, 256, 128, 1, 0);
    gemm_kernel<<<dim3(NROW/32, 2), 128, 0, stream>>>(feato, wkpT, b_kp, nullptr,
                                                      oe_bf, 288, 128, 1, 0);
    // 5: self-attn shared q=k=v projection (per-head bf16) + transpose
    gemm_kernel<<<dim3(NROW/32, 4), 128, 0, stream>>>(oe_bf, wsqT, ws_qb, nullptr,
                                                      kvbs, 128, 256, 2, 0);
    kvtrans_kernel<<<dim3(L_/32, B_*NH_), 256, 0, stream>>>(kvbs, kvT);
    // 6: self attention (flash v14: split staging)
    flash_attn_kernel<<<dim3(B_*NH_, L_/32), 256, 0, stream>>>(kvbs, kvbs, kvT,
                                                               nullptr, mobs, abuf);
    // 7: x = relu(oe + attn @ ws_o + ws_ob)
    gemm_kernel<<<dim3(NROW/32, 2), 128, 0, stream>>>(abuf, wsoT, ws_ob, oe_bf,
                                                      x_bf, 256, 128, 1, 1);
    // 8-13: mixing-weights path
    gemm_kernel<<<dim3(NROW/32, 4), 128, 0, stream>>>(x_bf, wwqT, ww_qb, nullptr,
                                                      kvmw, 128, 256, 2, 0);
    mwpartial_kernel<<<dim3(32, NH_, B_), 256, 0, stream>>>(qmwb, kvmw, mobs,
                                                            mwO, mwM, mwL);
    mwproj2_kernel<<<dim3(B_, G_), 256, 0, stream>>>(mwO, mwM, mwL, mix_wt,
                                                     ww_o, ww_ob, mwq);
    mwfinal_kernel<<<B_, 64, 0, stream>>>(mwq, w_mix, b_mix,
                                          out + (size_t)B_ * G_ * L_ * H_);
    // 14: merged cross projections: [qe_bf; x_bf](16384x128) @ wc_q -> [qcb; kvcb]
    gemm_kernel<<<dim3(2*NROW/32, 4), 128, 0, stream>>>(qe_bf, wcqT, wc_qb, nullptr,
                                                        qcb, 128, 256, 2, 0);
    kvtrans_kernel<<<dim3(L_/32, B_*NH_), 256, 0, stream>>>(kvcb, kvT);
    // 16: cross attention
    flash_attn_kernel<<<dim3(B_*NH_, L_/32), 256, 0, stream>>>(qcb, kvcb, kvT,
                                                               mq, mobs, abuf2);
    // 17: x2 = relu(qe + attn2 @ wc_o + wc_ob)
    gemm_kernel<<<dim3(NROW/32, 2), 128, 0, stream>>>(abuf2, wcoT, wc_ob, qe_bf,
                                                      x2_bf, 256, 128, 1, 1);
    // 18: split + transpose store (MFMA)
    gemm_kernel<<<dim3(NROW/32, 20), 128, 0, stream>>>(x2_bf, wsplT, b_split, nullptr,
                                                       out, 128, 1280, 3, 0);

    (void)in_sizes; (void)n_in; (void)out_size;
}